// Round 9
// baseline (362.783 us; speedup 1.0000x reference)
//
#include <hip/hip_runtime.h>
#include <hip/hip_fp16.h>

#define CHUNK 1024
#define RECB 24    // packed CSR record: {int src, int dst, 8x fp16 attr}

typedef _Float16 half8 __attribute__((ext_vector_type(8)));
typedef _Float16 half4 __attribute__((ext_vector_type(4)));
typedef float floatx4 __attribute__((ext_vector_type(4)));

union H8 { half8 h; unsigned int u[4]; };

__device__ __forceinline__ half8 hmax8(half8 a, half8 b) {
#if __has_builtin(__builtin_elementwise_max)
    return __builtin_elementwise_max(a, b);
#else
    half8 r;
    #pragma unroll
    for (int j = 0; j < 8; ++j) r[j] = a[j] > b[j] ? a[j] : b[j];
    return r;
#endif
}

__device__ __forceinline__ unsigned int pack2f(float a, float b) {
    __half2 h = __floats2half2_rn(a, b);
    return *(unsigned int*)&h;
}

__device__ __forceinline__ half8 load_attr(const char* __restrict__ rec, int et) {
    union { unsigned int u[4]; half8 h; } cv;
    uint2 lo = *(const uint2*)(rec + (size_t)et * RECB + 8);
    uint2 hi = *(const uint2*)(rec + (size_t)et * RECB + 16);
    cv.u[0] = lo.x; cv.u[1] = lo.y; cv.u[2] = hi.x; cv.u[3] = hi.y;
    return cv.h;
}

// ===========================================================================
// rank: r[e] = arrival index within src's segment.  4 edges/thread ->
// 4 INDEPENDENT atomicAdd chains in flight per thread (4x memory-level
// parallelism; the pass was latency-starved at 1 outstanding op/thread).
// Also converts x -> fp16 (xh).
// ===========================================================================
__global__ __launch_bounds__(256) void rank_cvt(
    const int* __restrict__ ei, const float* __restrict__ x,
    int* __restrict__ deg, unsigned short* __restrict__ r,
    _Float16* __restrict__ xh, int E, int N)
{
    int base = blockIdx.x * 1024 + threadIdx.x;
    int ev[4], sv[4];
    #pragma unroll
    for (int k = 0; k < 4; ++k) ev[k] = base + k * 256;
    #pragma unroll
    for (int k = 0; k < 4; ++k)
        sv[k] = (ev[k] < E) ? ei[ev[k]] : 0;
    unsigned short rv[4];
    #pragma unroll
    for (int k = 0; k < 4; ++k)
        if (ev[k] < E) rv[k] = (unsigned short)atomicAdd(&deg[sv[k]], 1);
    #pragma unroll
    for (int k = 0; k < 4; ++k)
        if (ev[k] < E) r[ev[k]] = rv[k];
    #pragma unroll
    for (int k = 0; k < 4; ++k)
        if (ev[k] < N) {
            float4 xv = *(const float4*)(x + (size_t)ev[k] * 4);
            half4 hx;
            hx[0] = (_Float16)xv.x; hx[1] = (_Float16)xv.y;
            hx[2] = (_Float16)xv.z; hx[3] = (_Float16)xv.w;
            *(half4*)(xh + (size_t)ev[k] * 4) = hx;
        }
}

__global__ __launch_bounds__(256) void scan_chunk_sums(
    const int* __restrict__ v, int* __restrict__ csum, int N)
{
    __shared__ int s[256];
    int base = blockIdx.x * CHUNK;
    int t = threadIdx.x;
    int acc = 0;
    #pragma unroll
    for (int i = 0; i < CHUNK / 256; ++i) {
        int idx = base + t + i * 256;
        if (idx < N) acc += v[idx];
    }
    s[t] = acc; __syncthreads();
    for (int o = 128; o > 0; o >>= 1) {
        if (t < o) s[t] += s[t + o];
        __syncthreads();
    }
    if (t == 0) csum[blockIdx.x] = s[0];
}

__global__ __launch_bounds__(256) void scan_chunk_off(
    const int* __restrict__ csum, int* __restrict__ coff, int nch)
{
    __shared__ int s[256];
    __shared__ int carry;
    int t = threadIdx.x;
    if (t == 0) carry = 0;
    __syncthreads();
    for (int base = 0; base < nch; base += 256) {
        int v = (base + t < nch) ? csum[base + t] : 0;
        s[t] = v; __syncthreads();
        for (int o = 1; o < 256; o <<= 1) {
            int add = (t >= o) ? s[t - o] : 0;
            __syncthreads();
            s[t] += add;
            __syncthreads();
        }
        int excl = carry + (t > 0 ? s[t - 1] : 0);
        if (base + t < nch) coff[base + t] = excl;
        __syncthreads();
        if (t == 0) carry += s[255];
        __syncthreads();
    }
}

__global__ __launch_bounds__(256) void scan_within_excl(
    const int* __restrict__ deg, int* __restrict__ pos,
    const int* __restrict__ coff, int N)
{
    __shared__ int s[256];
    int t = threadIdx.x;
    int base = blockIdx.x * CHUNK + t * 4;
    int v0 = 0, v1 = 0, v2 = 0, v3 = 0;
    if (base + 0 < N) v0 = deg[base + 0];
    if (base + 1 < N) v1 = deg[base + 1];
    if (base + 2 < N) v2 = deg[base + 2];
    if (base + 3 < N) v3 = deg[base + 3];
    s[t] = v0 + v1 + v2 + v3;
    __syncthreads();
    for (int o = 1; o < 256; o <<= 1) {
        int add = (t >= o) ? s[t - o] : 0;
        __syncthreads();
        s[t] += add;
        __syncthreads();
    }
    int run = coff[blockIdx.x] + (t > 0 ? s[t - 1] : 0);
    if (base + 0 < N) pos[base + 0] = run; run += v0;
    if (base + 1 < N) pos[base + 1] = run; run += v1;
    if (base + 2 < N) pos[base + 2] = run; run += v2;
    if (base + 3 < N) pos[base + 3] = run;
}

// ===========================================================================
// CSR record scatter: 4 edges/thread -> 12 independent scattered stores in
// flight per thread.  rec[p] = {src, dst, attr fp16}, p = pos[src] + r[e].
// ===========================================================================
__global__ __launch_bounds__(256) void scatter_rec(
    const int* __restrict__ ei, const float* __restrict__ ea,
    const int* __restrict__ pos, const unsigned short* __restrict__ r,
    char* __restrict__ rec, int E)
{
    int base = blockIdx.x * 1024 + threadIdx.x;
    #pragma unroll
    for (int k = 0; k < 4; ++k) {
        int e = base + k * 256;
        if (e < E) {
            int s = ei[e];
            int d = ei[E + e];
            int p = pos[s] + (int)r[e];
            float4 a0 = *(const float4*)(ea + (size_t)e * 8);
            float4 a1 = *(const float4*)(ea + (size_t)e * 8 + 4);
            unsigned int h0 = pack2f(a0.x, a0.y), h1 = pack2f(a0.z, a0.w);
            unsigned int h2 = pack2f(a1.x, a1.y), h3 = pack2f(a1.z, a1.w);
            char* b = rec + (size_t)p * RECB;
            *(int2*)b         = make_int2(s, d);
            *(uint2*)(b + 8)  = make_uint2(h0, h1);
            *(uint2*)(b + 16) = make_uint2(h2, h3);
        }
    }
}

// ===========================================================================
// conv1 edge-MLP over CSR-ordered records: ALL streams coalesced, m2h
// written coalesced at the edge's CSR position (= thread index).  TWO
// 64-edge macro-tiles per wave (8 x 16x16 MFMA tiles).
//   16x16x32 layouts: A[m=lane&15][k=8q+j], B[k=8q+j][n=lane&15],
//   C/D: col=lane&15, row=4q+reg.
// A k-map: q0 j0-3 = xh[src], j4-7 = xh[dst]; q1 j0-7 = attr; q2/q3 zero.
// ===========================================================================
__global__ __launch_bounds__(256) void edge_mlp1(
    const _Float16* __restrict__ xh,      // [N,4] fp16 (L2-resident gathers)
    const char*  __restrict__ rec,        // [E] 24B CSR records
    const float* __restrict__ w1, const float* __restrict__ b1,  // 16x16
    const float* __restrict__ w2, const float* __restrict__ b2,  // 16x16
    _Float16* __restrict__ m2h,           // [E,16] CSR-ordered out (coalesced)
    int E)
{
    __shared__ _Float16 itm[4][8][16][24];
    int tid = threadIdx.x;
    int w = tid >> 6, lane = tid & 63;
    int e16 = lane & 15, q = lane >> 4;
    int ebase = (blockIdx.x * 4 + w) << 7;    // 128 edges per wave
    if (ebase >= E) return;
    int e0 = ebase + lane;
    int e1 = ebase + 64 + lane;

    int s0 = 0, d0 = 0, s1 = 0, d1 = 0;
    if (e0 < E) { int2 p = *(const int2*)(rec + (size_t)e0 * RECB); s0 = p.x; d0 = p.y; }
    if (e1 < E) { int2 p = *(const int2*)(rec + (size_t)e1 * RECB); s1 = p.x; d1 = p.y; }

    half8 B1, B2;
    #pragma unroll
    for (int j = 0; j < 8; ++j) { B1[j] = (_Float16)0.f; B2[j] = (_Float16)0.f; }
    if (q < 2) {
        #pragma unroll
        for (int j = 0; j < 8; ++j) {
            B1[j] = (_Float16)w1[(8 * q + j) * 16 + e16];
            B2[j] = (_Float16)w2[(8 * q + j) * 16 + e16];
        }
    }
    float b1c = b1[e16], b2c = b2[e16];

    half8 A[8];
    #pragma unroll
    for (int t = 0; t < 8; ++t) {
        int tt = t & 3;
        int st = (t < 4) ? __shfl(s0, 16 * tt + e16, 64) : __shfl(s1, 16 * tt + e16, 64);
        int dt = (t < 4) ? __shfl(d0, 16 * tt + e16, 64) : __shfl(d1, 16 * tt + e16, 64);
        half8 a;
        #pragma unroll
        for (int j = 0; j < 8; ++j) a[j] = (_Float16)0.f;
        int et = ebase + 16 * t + e16;
        if (q == 0 && et < E) {
            half4 hs = *(const half4*)(xh + (size_t)st * 4);
            half4 hd = *(const half4*)(xh + (size_t)dt * 4);
            a[0] = hs[0]; a[1] = hs[1]; a[2] = hs[2]; a[3] = hs[3];
            a[4] = hd[0]; a[5] = hd[1]; a[6] = hd[2]; a[7] = hd[3];
        } else if (q == 1 && et < E) {
            a = load_attr(rec, et);
        }
        A[t] = a;
    }

    floatx4 C[8];
    #pragma unroll
    for (int t = 0; t < 8; ++t) {
        floatx4 c = {b1c, b1c, b1c, b1c};
        C[t] = __builtin_amdgcn_mfma_f32_16x16x32_f16(A[t], B1, c, 0, 0, 0);
    }
    #pragma unroll
    for (int t = 0; t < 8; ++t)
        #pragma unroll
        for (int i = 0; i < 4; ++i)
            itm[w][t][4 * q + i][e16] = (_Float16)fmaxf(C[t][i], 0.0f);
    __builtin_amdgcn_wave_barrier();

    half8 A2[8];
    #pragma unroll
    for (int t = 0; t < 8; ++t) {
        half8 a;
        #pragma unroll
        for (int j = 0; j < 8; ++j) a[j] = (_Float16)0.f;
        if (q < 2) a = *(const half8*)&itm[w][t][e16][8 * q];
        A2[t] = a;
    }
    __builtin_amdgcn_wave_barrier();
    floatx4 C2[8];
    #pragma unroll
    for (int t = 0; t < 8; ++t) {
        floatx4 c = {b2c, b2c, b2c, b2c};
        C2[t] = __builtin_amdgcn_mfma_f32_16x16x32_f16(A2[t], B2, c, 0, 0, 0);
    }
    #pragma unroll
    for (int t = 0; t < 8; ++t)
        #pragma unroll
        for (int i = 0; i < 4; ++i)
            itm[w][t][4 * q + i][e16] = (_Float16)C2[t][i];
    __builtin_amdgcn_wave_barrier();

    if (e0 < E) {
        half8 lo = *(const half8*)&itm[w][q][e16][0];
        half8 hi = *(const half8*)&itm[w][q][e16][8];
        *(half8*)(m2h + (size_t)e0 * 16)     = lo;   // coalesced (CSR order)
        *(half8*)(m2h + (size_t)e0 * 16 + 8) = hi;
    }
    if (e1 < E) {
        half8 lo = *(const half8*)&itm[w][q + 4][e16][0];
        half8 hi = *(const half8*)&itm[w][q + 4][e16][8];
        *(half8*)(m2h + (size_t)e1 * 16)     = lo;
        *(half8*)(m2h + (size_t)e1 * 16 + 8) = hi;
    }
}

// ===========================================================================
// conv2 edge-MLP over CSR records: layer-1 C-init via MFMA over gathered h1
// (one 16 B L2 gather per lane per tile); m2h coalesced write.
// A1 k-map (K=32): q0 = h1[src][0:8], q1 = h1[src][8:16],
//                  q2 = h1[dst][0:8], q3 = h1[dst][8:16]
// A2 k-map: q0 = attr (rows 32:40 of W1).
// C = mfma(A1, W1[0:32], mfma(A2, W1[32:40], b1))
// ===========================================================================
__global__ __launch_bounds__(256) void edge_mlp2(
    const _Float16* __restrict__ h1,           // [N,16] fp16
    const char*  __restrict__ rec,
    const float* __restrict__ w1, const float* __restrict__ b1v, // [40,16],[16]
    const float* __restrict__ w2, const float* __restrict__ b2,  // 16x16
    _Float16* __restrict__ m2h, int E)
{
    __shared__ _Float16 itm[4][8][16][24];
    int tid = threadIdx.x;
    int w = tid >> 6, lane = tid & 63;
    int e16 = lane & 15, q = lane >> 4;
    int ebase = (blockIdx.x * 4 + w) << 7;
    if (ebase >= E) return;
    int e0 = ebase + lane;
    int e1 = ebase + 64 + lane;

    int s0 = 0, d0 = 0, s1 = 0, d1 = 0;
    if (e0 < E) { int2 p = *(const int2*)(rec + (size_t)e0 * RECB); s0 = p.x; d0 = p.y; }
    if (e1 < E) { int2 p = *(const int2*)(rec + (size_t)e1 * RECB); s1 = p.x; d1 = p.y; }

    half8 B1, B2e, BL2;
    #pragma unroll
    for (int j = 0; j < 8; ++j) {
        B1[j] = (_Float16)w1[(8 * q + j) * 16 + e16];
        B2e[j] = (_Float16)0.f; BL2[j] = (_Float16)0.f;
    }
    if (q == 0) {
        #pragma unroll
        for (int j = 0; j < 8; ++j)
            B2e[j] = (_Float16)w1[(32 + j) * 16 + e16];
    }
    if (q < 2) {
        #pragma unroll
        for (int j = 0; j < 8; ++j)
            BL2[j] = (_Float16)w2[(8 * q + j) * 16 + e16];
    }
    float b1c = b1v[e16], b2c = b2[e16];

    half8 A1[8];
    #pragma unroll
    for (int t = 0; t < 8; ++t) {
        int tt = t & 3;
        int st = (t < 4) ? __shfl(s0, 16 * tt + e16, 64) : __shfl(s1, 16 * tt + e16, 64);
        int dt = (t < 4) ? __shfl(d0, 16 * tt + e16, 64) : __shfl(d1, 16 * tt + e16, 64);
        int row = (q < 2) ? st : dt;
        A1[t] = *(const half8*)(h1 + (size_t)row * 16 + 8 * (q & 1));
    }

    floatx4 C[8];
    #pragma unroll
    for (int t = 0; t < 8; ++t) {
        half8 a2;
        #pragma unroll
        for (int j = 0; j < 8; ++j) a2[j] = (_Float16)0.f;
        int et = ebase + 16 * t + e16;
        if (q == 0 && et < E)
            a2 = load_attr(rec, et);
        floatx4 c = {b1c, b1c, b1c, b1c};
        c = __builtin_amdgcn_mfma_f32_16x16x32_f16(a2, B2e, c, 0, 0, 0);
        C[t] = __builtin_amdgcn_mfma_f32_16x16x32_f16(A1[t], B1, c, 0, 0, 0);
    }
    #pragma unroll
    for (int t = 0; t < 8; ++t)
        #pragma unroll
        for (int i = 0; i < 4; ++i)
            itm[w][t][4 * q + i][e16] = (_Float16)fmaxf(C[t][i], 0.0f);
    __builtin_amdgcn_wave_barrier();

    half8 A2L[8];
    #pragma unroll
    for (int t = 0; t < 8; ++t) {
        half8 a;
        #pragma unroll
        for (int j = 0; j < 8; ++j) a[j] = (_Float16)0.f;
        if (q < 2) a = *(const half8*)&itm[w][t][e16][8 * q];
        A2L[t] = a;
    }
    __builtin_amdgcn_wave_barrier();
    floatx4 C2[8];
    #pragma unroll
    for (int t = 0; t < 8; ++t) {
        floatx4 c = {b2c, b2c, b2c, b2c};
        C2[t] = __builtin_amdgcn_mfma_f32_16x16x32_f16(A2L[t], BL2, c, 0, 0, 0);
    }
    #pragma unroll
    for (int t = 0; t < 8; ++t)
        #pragma unroll
        for (int i = 0; i < 4; ++i)
            itm[w][t][4 * q + i][e16] = (_Float16)C2[t][i];
    __builtin_amdgcn_wave_barrier();

    if (e0 < E) {
        half8 lo = *(const half8*)&itm[w][q][e16][0];
        half8 hi = *(const half8*)&itm[w][q][e16][8];
        *(half8*)(m2h + (size_t)e0 * 16)     = lo;
        *(half8*)(m2h + (size_t)e0 * 16 + 8) = hi;
    }
    if (e1 < E) {
        half8 lo = *(const half8*)&itm[w][q + 4][e16][0];
        half8 hi = *(const half8*)&itm[w][q + 4][e16][8];
        *(half8*)(m2h + (size_t)e1 * 16)     = lo;
        *(half8*)(m2h + (size_t)e1 * 16 + 8) = hi;
    }
}

// ===========================================================================
// Streaming segment-max (8 lanes/node), packed fp16 max, coalesced m2h.
// Segment n spans pos[n] .. pos[n+1].  acc init 0 == outer ReLU clamp +
// PyG empty fill.
// ===========================================================================
__global__ __launch_bounds__(256) void segmax1_h(
    const _Float16* __restrict__ m2h, const int* __restrict__ pos,
    unsigned int* __restrict__ h1u,     // [N,8] u32 (=16 fp16)
    int N, int E)
{
    int tid = threadIdx.x;
    int n = blockIdx.x * 32 + (tid >> 3);
    if (n >= N) return;
    int g = tid & 7;
    int start = pos[n];
    int end = (n + 1 < N) ? pos[n + 1] : E;

    half8 a0, a1;
    #pragma unroll
    for (int j = 0; j < 8; ++j) { a0[j] = (_Float16)0.f; a1[j] = (_Float16)0.f; }

    for (int k = start + g; k < end; k += 8) {
        half8 v0 = *(const half8*)(m2h + (size_t)k * 16);
        half8 v1 = *(const half8*)(m2h + (size_t)k * 16 + 8);
        a0 = hmax8(a0, v0);
        a1 = hmax8(a1, v1);
    }
    #pragma unroll
    for (int mask = 1; mask < 8; mask <<= 1) {
        H8 x0, x1, y0, y1;
        x0.h = a0; x1.h = a1;
        #pragma unroll
        for (int j = 0; j < 4; ++j) {
            y0.u[j] = __shfl_xor(x0.u[j], mask, 64);
            y1.u[j] = __shfl_xor(x1.u[j], mask, 64);
        }
        a0 = hmax8(a0, y0.h);
        a1 = hmax8(a1, y1.h);
    }
    H8 U0, U1; U0.h = a0; U1.h = a1;
    unsigned int word = (g < 4) ? U0.u[g & 3] : U1.u[g & 3];
    h1u[(size_t)n * 8 + g] = word;
}

__global__ __launch_bounds__(256) void segmax2_head(
    const _Float16* __restrict__ m2h, const int* __restrict__ pos,
    const float* __restrict__ l1w, const float* __restrict__ l1b,
    const float* __restrict__ l2w, const float* __restrict__ l2b,
    float* __restrict__ out, int N, int E)
{
    int tid = threadIdx.x;
    int n = blockIdx.x * 32 + (tid >> 3);
    if (n >= N) return;
    int g = tid & 7;
    int start = pos[n];
    int end = (n + 1 < N) ? pos[n + 1] : E;

    half8 a0, a1;
    #pragma unroll
    for (int j = 0; j < 8; ++j) { a0[j] = (_Float16)0.f; a1[j] = (_Float16)0.f; }

    for (int k = start + g; k < end; k += 8) {
        half8 v0 = *(const half8*)(m2h + (size_t)k * 16);
        half8 v1 = *(const half8*)(m2h + (size_t)k * 16 + 8);
        a0 = hmax8(a0, v0);
        a1 = hmax8(a1, v1);
    }
    #pragma unroll
    for (int mask = 1; mask < 8; mask <<= 1) {
        H8 x0, x1, y0, y1;
        x0.h = a0; x1.h = a1;
        #pragma unroll
        for (int j = 0; j < 4; ++j) {
            y0.u[j] = __shfl_xor(x0.u[j], mask, 64);
            y1.u[j] = __shfl_xor(x1.u[j], mask, 64);
        }
        a0 = hmax8(a0, y0.h);
        a1 = hmax8(a1, y1.h);
    }

    float acc[16];
    #pragma unroll
    for (int j = 0; j < 8; ++j) { acc[j] = (float)a0[j]; acc[8 + j] = (float)a1[j]; }

    float t2[16];
    #pragma unroll
    for (int j = 0; j < 16; ++j) t2[j] = l1b[j];
    #pragma unroll
    for (int kk = 0; kk < 16; ++kk) {
        float ak = acc[kk];
        #pragma unroll
        for (int j = 0; j < 16; ++j) t2[j] = fmaf(ak, l1w[kk * 16 + j], t2[j]);
    }
    float r2 = l2b[0];
    #pragma unroll
    for (int j = 0; j < 16; ++j) r2 = fmaf(fmaxf(t2[j], 0.0f), l2w[j], r2);
    if (g == 0) out[n] = r2;
}

// ===========================================================================
extern "C" void kernel_launch(void* const* d_in, const int* in_sizes, int n_in,
                              void* d_out, int out_size, void* d_ws, size_t ws_size,
                              hipStream_t stream)
{
    const float* x     = (const float*)d_in[0];
    const int*   ei    = (const int*)  d_in[1];
    const float* ea    = (const float*)d_in[2];
    const float* c1_w1 = (const float*)d_in[3];
    const float* c1_b1 = (const float*)d_in[4];
    const float* c1_w2 = (const float*)d_in[5];
    const float* c1_b2 = (const float*)d_in[6];
    const float* c2_w1 = (const float*)d_in[7];
    const float* c2_b1 = (const float*)d_in[8];
    const float* c2_w2 = (const float*)d_in[9];
    const float* c2_b2 = (const float*)d_in[10];
    const float* l1_w  = (const float*)d_in[11];
    const float* l1_b  = (const float*)d_in[12];
    const float* l2_w  = (const float*)d_in[13];
    const float* l2_b  = (const float*)d_in[14];
    float* out = (float*)d_out;

    const int N = in_sizes[0] / 4;   // 100000
    const int E = in_sizes[2] / 8;   // 1600000
    const int nch = (N + CHUNK - 1) / CHUNK;

    const int BLK = 256;
    const int e4grid = (E + 1023) / 1024;  // 4 edges/thread passes
    const int ggrid = (N + 31) / 32;
    const int mgrid = (E + 511) / 512;     // 512 edges per block (128/wave)

    size_t szPos = ((size_t)N * 4 + 15) & ~(size_t)15;   // 0.4 MB
    size_t szR   = ((size_t)E * 2 + 15) & ~(size_t)15;   // 3.2 MB
    size_t szXh  = ((size_t)N * 8 + 15) & ~(size_t)15;   // 0.8 MB
    size_t szH1  = ((size_t)N * 32 + 15) & ~(size_t)15;  // 3.2 MB
    size_t szRec = ((size_t)E * RECB + 15) & ~(size_t)15;// 38.4 MB
    size_t szM2h = (size_t)E * 32;                       // 51.2 MB

    size_t pos_off = 0;
    size_t r_off   = pos_off + szPos;
    size_t xh_off  = r_off   + szR;
    size_t h1_off  = xh_off  + szXh;
    size_t rec_off = h1_off  + szH1;
    size_t m2h_off = rec_off + szRec;
    // overlays inside m2h (dead until edge_mlp1 writes it):
    size_t deg_off = m2h_off;
    size_t cs_off  = deg_off + szPos;
    size_t cf_off  = cs_off + 4096;

    int*            pos  = (int*)  ((char*)d_ws + pos_off);
    unsigned short* r    = (unsigned short*)((char*)d_ws + r_off);
    _Float16*       xh   = (_Float16*)((char*)d_ws + xh_off);
    _Float16*       h1   = (_Float16*)((char*)d_ws + h1_off);
    char*           rec  = (char*) ((char*)d_ws + rec_off);
    _Float16*       m2h  = (_Float16*)((char*)d_ws + m2h_off);
    int*            deg  = (int*)  ((char*)d_ws + deg_off);
    int*            csum = (int*)  ((char*)d_ws + cs_off);
    int*            coff = (int*)  ((char*)d_ws + cf_off);

    hipMemsetAsync(deg, 0, (size_t)N * 4, stream);
    rank_cvt<<<e4grid, BLK, 0, stream>>>(ei, x, deg, r, xh, E, N);
    scan_chunk_sums<<<nch, BLK, 0, stream>>>(deg, csum, N);
    scan_chunk_off<<<1, 256, 0, stream>>>(csum, coff, nch);
    scan_within_excl<<<nch, BLK, 0, stream>>>(deg, pos, coff, N);
    scatter_rec<<<e4grid, BLK, 0, stream>>>(ei, ea, pos, r, rec, E);
    edge_mlp1<<<mgrid, BLK, 0, stream>>>(xh, rec,
                                         c1_w1, c1_b1, c1_w2, c1_b2, m2h, E);
    segmax1_h<<<ggrid, BLK, 0, stream>>>(m2h, pos, (unsigned int*)h1, N, E);
    edge_mlp2<<<mgrid, BLK, 0, stream>>>(h1, rec,
                                         c2_w1, c2_b1, c2_w2, c2_b2, m2h, E);
    segmax2_head<<<ggrid, BLK, 0, stream>>>(m2h, pos, l1_w, l1_b, l2_w, l2_b,
                                            out, N, E);
}

// Round 10
// 324.949 us; speedup vs baseline: 1.1164x; 1.1164x over previous
//
#include <hip/hip_runtime.h>
#include <hip/hip_fp16.h>

#define CHUNK 1024
#define RECB 24    // packed CSR record: {int src, int dst, 8x fp16 attr}
#define SPAN 192   // max node-span of a 512-edge CSR block handled in LDS

typedef _Float16 half8 __attribute__((ext_vector_type(8)));
typedef _Float16 half4 __attribute__((ext_vector_type(4)));
typedef float floatx4 __attribute__((ext_vector_type(4)));

__device__ __forceinline__ unsigned int pack2f(float a, float b) {
    __half2 h = __floats2half2_rn(a, b);
    return *(unsigned int*)&h;
}

__device__ __forceinline__ half8 load_attr(const char* __restrict__ rec, int et) {
    union { unsigned int u[4]; half8 h; } cv;
    uint2 lo = *(const uint2*)(rec + (size_t)et * RECB + 8);
    uint2 hi = *(const uint2*)(rec + (size_t)et * RECB + 16);
    cv.u[0] = lo.x; cv.u[1] = lo.y; cv.u[2] = hi.x; cv.u[3] = hi.y;
    return cv.h;
}

// ===========================================================================
// rank: r[e] = arrival index within src's segment (1 edge/thread — round-9
// showed the atomic wall is throughput-side; batching only hurt occupancy).
// Also converts x -> fp16 (xh).
// ===========================================================================
__global__ __launch_bounds__(256) void rank_cvt(
    const int* __restrict__ ei, const float* __restrict__ x,
    int* __restrict__ deg, unsigned short* __restrict__ r,
    _Float16* __restrict__ xh, int E, int N)
{
    int e = blockIdx.x * 256 + threadIdx.x;
    if (e >= E) return;
    r[e] = (unsigned short)atomicAdd(&deg[ei[e]], 1);
    if (e < N) {
        float4 xv = *(const float4*)(x + (size_t)e * 4);
        half4 hx;
        hx[0] = (_Float16)xv.x; hx[1] = (_Float16)xv.y;
        hx[2] = (_Float16)xv.z; hx[3] = (_Float16)xv.w;
        *(half4*)(xh + (size_t)e * 4) = hx;
    }
}

__global__ __launch_bounds__(256) void scan_chunk_sums(
    const int* __restrict__ v, int* __restrict__ csum, int N)
{
    __shared__ int s[256];
    int base = blockIdx.x * CHUNK;
    int t = threadIdx.x;
    int acc = 0;
    #pragma unroll
    for (int i = 0; i < CHUNK / 256; ++i) {
        int idx = base + t + i * 256;
        if (idx < N) acc += v[idx];
    }
    s[t] = acc; __syncthreads();
    for (int o = 128; o > 0; o >>= 1) {
        if (t < o) s[t] += s[t + o];
        __syncthreads();
    }
    if (t == 0) csum[blockIdx.x] = s[0];
}

__global__ __launch_bounds__(256) void scan_chunk_off(
    const int* __restrict__ csum, int* __restrict__ coff, int nch)
{
    __shared__ int s[256];
    __shared__ int carry;
    int t = threadIdx.x;
    if (t == 0) carry = 0;
    __syncthreads();
    for (int base = 0; base < nch; base += 256) {
        int v = (base + t < nch) ? csum[base + t] : 0;
        s[t] = v; __syncthreads();
        for (int o = 1; o < 256; o <<= 1) {
            int add = (t >= o) ? s[t - o] : 0;
            __syncthreads();
            s[t] += add;
            __syncthreads();
        }
        int excl = carry + (t > 0 ? s[t - 1] : 0);
        if (base + t < nch) coff[base + t] = excl;
        __syncthreads();
        if (t == 0) carry += s[255];
        __syncthreads();
    }
}

__global__ __launch_bounds__(256) void scan_within_excl(
    const int* __restrict__ deg, int* __restrict__ pos,
    const int* __restrict__ coff, int N)
{
    __shared__ int s[256];
    int t = threadIdx.x;
    int base = blockIdx.x * CHUNK + t * 4;
    int v0 = 0, v1 = 0, v2 = 0, v3 = 0;
    if (base + 0 < N) v0 = deg[base + 0];
    if (base + 1 < N) v1 = deg[base + 1];
    if (base + 2 < N) v2 = deg[base + 2];
    if (base + 3 < N) v3 = deg[base + 3];
    s[t] = v0 + v1 + v2 + v3;
    __syncthreads();
    for (int o = 1; o < 256; o <<= 1) {
        int add = (t >= o) ? s[t - o] : 0;
        __syncthreads();
        s[t] += add;
        __syncthreads();
    }
    int run = coff[blockIdx.x] + (t > 0 ? s[t - 1] : 0);
    if (base + 0 < N) pos[base + 0] = run; run += v0;
    if (base + 1 < N) pos[base + 1] = run; run += v1;
    if (base + 2 < N) pos[base + 2] = run; run += v2;
    if (base + 3 < N) pos[base + 3] = run;
}

// ===========================================================================
// CSR record scatter (1 edge/thread — round-9 regression reverted).
// rec[p] = {src, dst, attr fp16}, p = pos[src] + r[e].
// ===========================================================================
__global__ __launch_bounds__(256) void scatter_rec(
    const int* __restrict__ ei, const float* __restrict__ ea,
    const int* __restrict__ pos, const unsigned short* __restrict__ r,
    char* __restrict__ rec, int E)
{
    int e = blockIdx.x * 256 + threadIdx.x;
    if (e >= E) return;
    int s = ei[e];
    int d = ei[E + e];
    int p = pos[s] + (int)r[e];
    float4 a0 = *(const float4*)(ea + (size_t)e * 8);
    float4 a1 = *(const float4*)(ea + (size_t)e * 8 + 4);
    unsigned int h0 = pack2f(a0.x, a0.y), h1 = pack2f(a0.z, a0.w);
    unsigned int h2 = pack2f(a1.x, a1.y), h3 = pack2f(a1.z, a1.w);
    char* b = rec + (size_t)p * RECB;
    *(int2*)b         = make_int2(s, d);
    *(uint2*)(b + 8)  = make_uint2(h0, h1);
    *(uint2*)(b + 16) = make_uint2(h2, h3);
}

// ===========================================================================
// conv1 edge-MLP + FUSED segmented max.  Block = 512 CSR-consecutive edges
// (4 waves x 2 macro-tiles).  Layer-2 outputs (ReLU'd >=0) are max-reduced
// via LDS int atomicMax into lmax[span][16]; CSR contiguity means interior
// nodes of the block's span are owned exclusively -> plain coalesced store;
// only the 2 boundary nodes use global atomicMax (~100k total, way under
// the random-store wall).  m2h/segmax kernels eliminated.
//   16x16x32 layouts: A[m=lane&15][k=8q+j], B[k=8q+j][n=lane&15],
//   C/D: col=lane&15, row=4q+reg.
// ===========================================================================
__global__ __launch_bounds__(256) void edge_mlp1_agg(
    const _Float16* __restrict__ xh,      // [N,4] fp16 (L2-resident gathers)
    const char*  __restrict__ rec,        // [E] 24B CSR records
    const float* __restrict__ w1, const float* __restrict__ b1,  // 16x16
    const float* __restrict__ w2, const float* __restrict__ b2,  // 16x16
    int* __restrict__ aggi,               // [N,16] f32-bits, memset 0
    int E)
{
    __shared__ _Float16 itm[4][8][16][24];
    __shared__ int lmax[SPAN * 16];
    int tid = threadIdx.x;
    int w = tid >> 6, lane = tid & 63;
    int e16 = lane & 15, q = lane >> 4;
    int kb = blockIdx.x * 512;
    int ebase = kb + (w << 7);            // 128 edges per wave
    int e0 = ebase + lane;
    int e1 = ebase + 64 + lane;

    #pragma unroll
    for (int i = 0; i < SPAN * 16 / 256; ++i) lmax[tid + i * 256] = 0;

    int klast = min(kb + 511, E - 1);
    int n_first = *(const int*)(rec + (size_t)kb * RECB);
    int n_last  = *(const int*)(rec + (size_t)klast * RECB);
    int span = n_last - n_first + 1;
    bool fb = (span > SPAN);
    __syncthreads();

    int s0 = 0, d0 = 0, s1 = 0, d1 = 0;
    if (e0 < E) { int2 p = *(const int2*)(rec + (size_t)e0 * RECB); s0 = p.x; d0 = p.y; }
    if (e1 < E) { int2 p = *(const int2*)(rec + (size_t)e1 * RECB); s1 = p.x; d1 = p.y; }

    half8 B1, B2;
    #pragma unroll
    for (int j = 0; j < 8; ++j) { B1[j] = (_Float16)0.f; B2[j] = (_Float16)0.f; }
    if (q < 2) {
        #pragma unroll
        for (int j = 0; j < 8; ++j) {
            B1[j] = (_Float16)w1[(8 * q + j) * 16 + e16];
            B2[j] = (_Float16)w2[(8 * q + j) * 16 + e16];
        }
    }
    float b1c = b1[e16], b2c = b2[e16];

    half8 A[8];
    #pragma unroll
    for (int t = 0; t < 8; ++t) {
        int tt = t & 3;
        int st = (t < 4) ? __shfl(s0, 16 * tt + e16, 64) : __shfl(s1, 16 * tt + e16, 64);
        int dt = (t < 4) ? __shfl(d0, 16 * tt + e16, 64) : __shfl(d1, 16 * tt + e16, 64);
        half8 a;
        #pragma unroll
        for (int j = 0; j < 8; ++j) a[j] = (_Float16)0.f;
        int et = ebase + 16 * t + e16;
        if (q == 0 && et < E) {
            half4 hs = *(const half4*)(xh + (size_t)st * 4);
            half4 hd = *(const half4*)(xh + (size_t)dt * 4);
            a[0] = hs[0]; a[1] = hs[1]; a[2] = hs[2]; a[3] = hs[3];
            a[4] = hd[0]; a[5] = hd[1]; a[6] = hd[2]; a[7] = hd[3];
        } else if (q == 1 && et < E) {
            a = load_attr(rec, et);
        }
        A[t] = a;
    }

    floatx4 C[8];
    #pragma unroll
    for (int t = 0; t < 8; ++t) {
        floatx4 c = {b1c, b1c, b1c, b1c};
        C[t] = __builtin_amdgcn_mfma_f32_16x16x32_f16(A[t], B1, c, 0, 0, 0);
    }
    #pragma unroll
    for (int t = 0; t < 8; ++t)
        #pragma unroll
        for (int i = 0; i < 4; ++i)
            itm[w][t][4 * q + i][e16] = (_Float16)fmaxf(C[t][i], 0.0f);
    __builtin_amdgcn_wave_barrier();

    half8 A2[8];
    #pragma unroll
    for (int t = 0; t < 8; ++t) {
        half8 a;
        #pragma unroll
        for (int j = 0; j < 8; ++j) a[j] = (_Float16)0.f;
        if (q < 2) a = *(const half8*)&itm[w][t][e16][8 * q];
        A2[t] = a;
    }
    __builtin_amdgcn_wave_barrier();
    floatx4 C2[8];
    #pragma unroll
    for (int t = 0; t < 8; ++t) {
        floatx4 c = {b2c, b2c, b2c, b2c};
        C2[t] = __builtin_amdgcn_mfma_f32_16x16x32_f16(A2[t], B2, c, 0, 0, 0);
    }

    // fused segmented max: lane holds channel e16 of edge ebase+16t+(4q+i)
    #pragma unroll
    for (int t = 0; t < 8; ++t) {
        int tt = t & 3;
        #pragma unroll
        for (int i = 0; i < 4; ++i) {
            int rr = 4 * q + i;
            int nn = (t < 4) ? __shfl(s0, 16 * tt + rr, 64) : __shfl(s1, 16 * tt + rr, 64);
            int et = ebase + 16 * t + rr;
            if (et < E) {
                int bits = __float_as_int(fmaxf(C2[t][i], 0.0f));
                if (!fb) atomicMax(&lmax[(nn - n_first) * 16 + e16], bits);
                else     atomicMax(&aggi[(size_t)nn * 16 + e16], bits);
            }
        }
    }
    __syncthreads();
    if (!fb) {
        int tot = span * 16;
        for (int idx = tid; idx < tot; idx += 256) {
            int row = idx >> 4;
            int nn = n_first + row;
            int v = lmax[idx];
            if (nn == n_first || nn == n_last) {
                if (v != 0) atomicMax(&aggi[(size_t)nn * 16 + (idx & 15)], v);
            } else {
                aggi[(size_t)nn * 16 + (idx & 15)] = v;
            }
        }
    }
}

// agg1 (f32 bits) -> h1 fp16, packed pairs
__global__ __launch_bounds__(256) void cvt_h1(
    const int* __restrict__ aggi, unsigned int* __restrict__ h1u, int total)
{
    int i = blockIdx.x * 256 + threadIdx.x;
    if (i >= total) return;
    int2 v = *(const int2*)(aggi + 2 * i);
    h1u[i] = pack2f(__int_as_float(v.x), __int_as_float(v.y));
}

// ===========================================================================
// conv2 edge-MLP + fused segmented max.  Layer-1 C-init via MFMA over
// gathered h1 (one 16 B L2 gather per lane per tile).
// A1 k-map (K=32): q0 = h1[src][0:8], q1 = h1[src][8:16],
//                  q2 = h1[dst][0:8], q3 = h1[dst][8:16]
// A2 k-map: q0 = attr (rows 32:40 of W1).
// C = mfma(A1, W1[0:32], mfma(A2, W1[32:40], b1))
// ===========================================================================
__global__ __launch_bounds__(256) void edge_mlp2_agg(
    const _Float16* __restrict__ h1,           // [N,16] fp16
    const char*  __restrict__ rec,
    const float* __restrict__ w1, const float* __restrict__ b1v, // [40,16],[16]
    const float* __restrict__ w2, const float* __restrict__ b2,  // 16x16
    int* __restrict__ aggi, int E)
{
    __shared__ _Float16 itm[4][8][16][24];
    __shared__ int lmax[SPAN * 16];
    int tid = threadIdx.x;
    int w = tid >> 6, lane = tid & 63;
    int e16 = lane & 15, q = lane >> 4;
    int kb = blockIdx.x * 512;
    int ebase = kb + (w << 7);
    int e0 = ebase + lane;
    int e1 = ebase + 64 + lane;

    #pragma unroll
    for (int i = 0; i < SPAN * 16 / 256; ++i) lmax[tid + i * 256] = 0;

    int klast = min(kb + 511, E - 1);
    int n_first = *(const int*)(rec + (size_t)kb * RECB);
    int n_last  = *(const int*)(rec + (size_t)klast * RECB);
    int span = n_last - n_first + 1;
    bool fb = (span > SPAN);
    __syncthreads();

    int s0 = 0, d0 = 0, s1 = 0, d1 = 0;
    if (e0 < E) { int2 p = *(const int2*)(rec + (size_t)e0 * RECB); s0 = p.x; d0 = p.y; }
    if (e1 < E) { int2 p = *(const int2*)(rec + (size_t)e1 * RECB); s1 = p.x; d1 = p.y; }

    half8 B1, B2e, BL2;
    #pragma unroll
    for (int j = 0; j < 8; ++j) {
        B1[j] = (_Float16)w1[(8 * q + j) * 16 + e16];
        B2e[j] = (_Float16)0.f; BL2[j] = (_Float16)0.f;
    }
    if (q == 0) {
        #pragma unroll
        for (int j = 0; j < 8; ++j)
            B2e[j] = (_Float16)w1[(32 + j) * 16 + e16];
    }
    if (q < 2) {
        #pragma unroll
        for (int j = 0; j < 8; ++j)
            BL2[j] = (_Float16)w2[(8 * q + j) * 16 + e16];
    }
    float b1c = b1v[e16], b2c = b2[e16];

    half8 A1[8];
    #pragma unroll
    for (int t = 0; t < 8; ++t) {
        int tt = t & 3;
        int st = (t < 4) ? __shfl(s0, 16 * tt + e16, 64) : __shfl(s1, 16 * tt + e16, 64);
        int dt = (t < 4) ? __shfl(d0, 16 * tt + e16, 64) : __shfl(d1, 16 * tt + e16, 64);
        int row = (q < 2) ? st : dt;
        A1[t] = *(const half8*)(h1 + (size_t)row * 16 + 8 * (q & 1));
    }

    floatx4 C[8];
    #pragma unroll
    for (int t = 0; t < 8; ++t) {
        half8 a2;
        #pragma unroll
        for (int j = 0; j < 8; ++j) a2[j] = (_Float16)0.f;
        int et = ebase + 16 * t + e16;
        if (q == 0 && et < E)
            a2 = load_attr(rec, et);
        floatx4 c = {b1c, b1c, b1c, b1c};
        c = __builtin_amdgcn_mfma_f32_16x16x32_f16(a2, B2e, c, 0, 0, 0);
        C[t] = __builtin_amdgcn_mfma_f32_16x16x32_f16(A1[t], B1, c, 0, 0, 0);
    }
    #pragma unroll
    for (int t = 0; t < 8; ++t)
        #pragma unroll
        for (int i = 0; i < 4; ++i)
            itm[w][t][4 * q + i][e16] = (_Float16)fmaxf(C[t][i], 0.0f);
    __builtin_amdgcn_wave_barrier();

    half8 A2L[8];
    #pragma unroll
    for (int t = 0; t < 8; ++t) {
        half8 a;
        #pragma unroll
        for (int j = 0; j < 8; ++j) a[j] = (_Float16)0.f;
        if (q < 2) a = *(const half8*)&itm[w][t][e16][8 * q];
        A2L[t] = a;
    }
    __builtin_amdgcn_wave_barrier();
    floatx4 C2[8];
    #pragma unroll
    for (int t = 0; t < 8; ++t) {
        floatx4 c = {b2c, b2c, b2c, b2c};
        C2[t] = __builtin_amdgcn_mfma_f32_16x16x32_f16(A2L[t], BL2, c, 0, 0, 0);
    }

    #pragma unroll
    for (int t = 0; t < 8; ++t) {
        int tt = t & 3;
        #pragma unroll
        for (int i = 0; i < 4; ++i) {
            int rr = 4 * q + i;
            int nn = (t < 4) ? __shfl(s0, 16 * tt + rr, 64) : __shfl(s1, 16 * tt + rr, 64);
            int et = ebase + 16 * t + rr;
            if (et < E) {
                int bits = __float_as_int(fmaxf(C2[t][i], 0.0f));
                if (!fb) atomicMax(&lmax[(nn - n_first) * 16 + e16], bits);
                else     atomicMax(&aggi[(size_t)nn * 16 + e16], bits);
            }
        }
    }
    __syncthreads();
    if (!fb) {
        int tot = span * 16;
        for (int idx = tid; idx < tot; idx += 256) {
            int row = idx >> 4;
            int nn = n_first + row;
            int v = lmax[idx];
            if (nn == n_first || nn == n_last) {
                if (v != 0) atomicMax(&aggi[(size_t)nn * 16 + (idx & 15)], v);
            } else {
                aggi[(size_t)nn * 16 + (idx & 15)] = v;
            }
        }
    }
}

// ===========================================================================
// Dense per-node head: h2 -> relu(h2@l1+b) @ l2 + b
// ===========================================================================
__global__ __launch_bounds__(256) void head_out(
    const int* __restrict__ aggi,
    const float* __restrict__ l1w, const float* __restrict__ l1b,
    const float* __restrict__ l2w, const float* __restrict__ l2b,
    float* __restrict__ out, int N)
{
    int n = blockIdx.x * 256 + threadIdx.x;
    if (n >= N) return;
    const float4* ar = (const float4*)(aggi + (size_t)n * 16);
    float4 A0 = ar[0], A1 = ar[1], A2 = ar[2], A3 = ar[3];
    float acc[16] = {A0.x, A0.y, A0.z, A0.w, A1.x, A1.y, A1.z, A1.w,
                     A2.x, A2.y, A2.z, A2.w, A3.x, A3.y, A3.z, A3.w};
    float t2[16];
    #pragma unroll
    for (int j = 0; j < 16; ++j) t2[j] = l1b[j];
    #pragma unroll
    for (int k = 0; k < 16; ++k) {
        float ak = acc[k];
        #pragma unroll
        for (int j = 0; j < 16; ++j) t2[j] = fmaf(ak, l1w[k * 16 + j], t2[j]);
    }
    float r2 = l2b[0];
    #pragma unroll
    for (int j = 0; j < 16; ++j) r2 = fmaf(fmaxf(t2[j], 0.0f), l2w[j], r2);
    out[n] = r2;
}

// ===========================================================================
extern "C" void kernel_launch(void* const* d_in, const int* in_sizes, int n_in,
                              void* d_out, int out_size, void* d_ws, size_t ws_size,
                              hipStream_t stream)
{
    const float* x     = (const float*)d_in[0];
    const int*   ei    = (const int*)  d_in[1];
    const float* ea    = (const float*)d_in[2];
    const float* c1_w1 = (const float*)d_in[3];
    const float* c1_b1 = (const float*)d_in[4];
    const float* c1_w2 = (const float*)d_in[5];
    const float* c1_b2 = (const float*)d_in[6];
    const float* c2_w1 = (const float*)d_in[7];
    const float* c2_b1 = (const float*)d_in[8];
    const float* c2_w2 = (const float*)d_in[9];
    const float* c2_b2 = (const float*)d_in[10];
    const float* l1_w  = (const float*)d_in[11];
    const float* l1_b  = (const float*)d_in[12];
    const float* l2_w  = (const float*)d_in[13];
    const float* l2_b  = (const float*)d_in[14];
    float* out = (float*)d_out;

    const int N = in_sizes[0] / 4;   // 100000
    const int E = in_sizes[2] / 8;   // 1600000
    const int nch = (N + CHUNK - 1) / CHUNK;

    const int BLK = 256;
    const int egrid = (E + BLK - 1) / BLK;
    const int mgrid = (E + 511) / 512;     // 512 CSR edges per block
    const int ngrid = (N + 255) / 256;
    const int cgrid = (N * 8 + 255) / 256; // cvt_h1: N*16/2 words

    size_t szPos = ((size_t)N * 4 + 255) & ~(size_t)255;    // 0.4 MB
    size_t szR   = ((size_t)E * 2 + 255) & ~(size_t)255;    // 3.2 MB
    size_t szXh  = ((size_t)N * 8 + 255) & ~(size_t)255;    // 0.8 MB
    size_t szH1  = ((size_t)N * 32 + 255) & ~(size_t)255;   // 3.2 MB
    size_t szRec = ((size_t)E * RECB + 255) & ~(size_t)255; // 38.4 MB
    size_t szAgg = ((size_t)N * 16 * 4 + 255) & ~(size_t)255; // 6.4 MB
    size_t szDeg = szPos;

    size_t pos_off  = 0;
    size_t r_off    = pos_off  + szPos;
    size_t xh_off   = r_off    + szR;
    size_t h1_off   = xh_off   + szXh;
    size_t rec_off  = h1_off   + szH1;
    size_t agg1_off = rec_off  + szRec;
    size_t agg2_off = agg1_off + szAgg;
    size_t deg_off  = agg2_off + szAgg;
    size_t cs_off   = deg_off  + szDeg;
    size_t cf_off   = cs_off   + 4096;

    int*            pos  = (int*)  ((char*)d_ws + pos_off);
    unsigned short* r    = (unsigned short*)((char*)d_ws + r_off);
    _Float16*       xh   = (_Float16*)((char*)d_ws + xh_off);
    _Float16*       h1   = (_Float16*)((char*)d_ws + h1_off);
    char*           rec  = (char*) ((char*)d_ws + rec_off);
    int*            agg1 = (int*)  ((char*)d_ws + agg1_off);
    int*            agg2 = (int*)  ((char*)d_ws + agg2_off);
    int*            deg  = (int*)  ((char*)d_ws + deg_off);
    int*            csum = (int*)  ((char*)d_ws + cs_off);
    int*            coff = (int*)  ((char*)d_ws + cf_off);

    hipMemsetAsync(deg, 0, (size_t)N * 4, stream);
    hipMemsetAsync(agg1, 0, (size_t)N * 64, stream);
    hipMemsetAsync(agg2, 0, (size_t)N * 64, stream);
    rank_cvt<<<egrid, BLK, 0, stream>>>(ei, x, deg, r, xh, E, N);
    scan_chunk_sums<<<nch, BLK, 0, stream>>>(deg, csum, N);
    scan_chunk_off<<<1, 256, 0, stream>>>(csum, coff, nch);
    scan_within_excl<<<nch, BLK, 0, stream>>>(deg, pos, coff, N);
    scatter_rec<<<egrid, BLK, 0, stream>>>(ei, ea, pos, r, rec, E);
    edge_mlp1_agg<<<mgrid, BLK, 0, stream>>>(xh, rec,
                                             c1_w1, c1_b1, c1_w2, c1_b2,
                                             agg1, E);
    cvt_h1<<<cgrid, BLK, 0, stream>>>(agg1, (unsigned int*)h1, N * 8);
    edge_mlp2_agg<<<mgrid, BLK, 0, stream>>>(h1, rec,
                                             c2_w1, c2_b1, c2_w2, c2_b2,
                                             agg2, E);
    head_out<<<ngrid, BLK, 0, stream>>>(agg2, l1_w, l1_b, l2_w, l2_b, out, N);
}

// Round 11
// 303.658 us; speedup vs baseline: 1.1947x; 1.0701x over previous
//
#include <hip/hip_runtime.h>
#include <hip/hip_fp16.h>

#define CHUNK 1024
#define NBLK 256   // blocks in hist/partition passes
#define NSH  9     // nodes per bucket = 512
#define SPAN 192   // max node-span of a 512-edge CSR block handled in LDS

typedef _Float16 half8 __attribute__((ext_vector_type(8)));
typedef _Float16 half4 __attribute__((ext_vector_type(4)));
typedef float floatx4 __attribute__((ext_vector_type(4)));

__device__ __forceinline__ unsigned int pack2f(float a, float b) {
    __half2 h = __floats2half2_rn(a, b);
    return *(unsigned int*)&h;
}

__device__ __forceinline__ half8 load_attr(const uint4* __restrict__ rat, int et) {
    union { uint4 u; half8 h; } cv;
    cv.u = rat[et];
    return cv.h;
}

// ===========================================================================
// Pass A: per-block LDS bucket histogram (bucket = src>>9, 196 buckets) +
// x -> fp16.  NO global atomics: 1.6M LDS atomics instead of memory-side RMW.
// cnt is [bucket][block] (bucket-major) so one flat exclusive scan yields
// every (block,bucket) run base directly.
// ===========================================================================
__global__ __launch_bounds__(512) void hist_x(
    const int* __restrict__ ei, const float* __restrict__ x,
    int* __restrict__ cnt, _Float16* __restrict__ xh,
    int E, int N, int nbk, int epb)
{
    __shared__ int h[256];
    int t = threadIdx.x, b = blockIdx.x;
    if (t < 256) h[t] = 0;
    __syncthreads();
    int est = b * epb;
    int een = min(E, est + epb);
    for (int e = est + t; e < een; e += 512)
        atomicAdd(&h[ei[e] >> NSH], 1);
    for (int i = est + t; i < een; i += 512)
        if (i < N) {
            float4 xv = *(const float4*)(x + (size_t)i * 4);
            half4 hx;
            hx[0] = (_Float16)xv.x; hx[1] = (_Float16)xv.y;
            hx[2] = (_Float16)xv.z; hx[3] = (_Float16)xv.w;
            *(half4*)(xh + (size_t)i * 4) = hx;
        }
    __syncthreads();
    if (t < nbk) cnt[t * NBLK + b] = h[t];
}

__global__ __launch_bounds__(256) void scan_chunk_sums(
    const int* __restrict__ v, int* __restrict__ csum, int N)
{
    __shared__ int s[256];
    int base = blockIdx.x * CHUNK;
    int t = threadIdx.x;
    int acc = 0;
    #pragma unroll
    for (int i = 0; i < CHUNK / 256; ++i) {
        int idx = base + t + i * 256;
        if (idx < N) acc += v[idx];
    }
    s[t] = acc; __syncthreads();
    for (int o = 128; o > 0; o >>= 1) {
        if (t < o) s[t] += s[t + o];
        __syncthreads();
    }
    if (t == 0) csum[blockIdx.x] = s[0];
}

__global__ __launch_bounds__(256) void scan_chunk_off(
    const int* __restrict__ csum, int* __restrict__ coff, int nch)
{
    __shared__ int s[256];
    __shared__ int carry;
    int t = threadIdx.x;
    if (t == 0) carry = 0;
    __syncthreads();
    for (int base = 0; base < nch; base += 256) {
        int v = (base + t < nch) ? csum[base + t] : 0;
        s[t] = v; __syncthreads();
        for (int o = 1; o < 256; o <<= 1) {
            int add = (t >= o) ? s[t - o] : 0;
            __syncthreads();
            s[t] += add;
            __syncthreads();
        }
        int excl = carry + (t > 0 ? s[t - 1] : 0);
        if (base + t < nch) coff[base + t] = excl;
        __syncthreads();
        if (t == 0) carry += s[255];
        __syncthreads();
    }
}

__global__ __launch_bounds__(256) void scan_within_excl(
    const int* __restrict__ deg, int* __restrict__ pos,
    const int* __restrict__ coff, int N)
{
    __shared__ int s[256];
    int t = threadIdx.x;
    int base = blockIdx.x * CHUNK + t * 4;
    int v0 = 0, v1 = 0, v2 = 0, v3 = 0;
    if (base + 0 < N) v0 = deg[base + 0];
    if (base + 1 < N) v1 = deg[base + 1];
    if (base + 2 < N) v2 = deg[base + 2];
    if (base + 3 < N) v3 = deg[base + 3];
    s[t] = v0 + v1 + v2 + v3;
    __syncthreads();
    for (int o = 1; o < 256; o <<= 1) {
        int add = (t >= o) ? s[t - o] : 0;
        __syncthreads();
        s[t] += add;
        __syncthreads();
    }
    int run = coff[blockIdx.x] + (t > 0 ? s[t - 1] : 0);
    if (base + 0 < N) pos[base + 0] = run; run += v0;
    if (base + 1 < N) pos[base + 1] = run; run += v1;
    if (base + 2 < N) pos[base + 2] = run; run += v2;
    if (base + 3 < N) pos[base + 3] = run;
}

// ===========================================================================
// Pass C: partition edges into bucket-major order.  LDS cursors (no global
// atomics); each (block,bucket) run is contiguous (~32 edges) -> writes are
// short coalesced bursts, not random lines.  SoA: sd int2 + at uint4.
// ===========================================================================
__global__ __launch_bounds__(512) void partition(
    const int* __restrict__ ei, const float* __restrict__ ea,
    const int* __restrict__ off,
    int2* __restrict__ p1sd, uint4* __restrict__ p1at,
    int E, int nbk, int epb)
{
    __shared__ int cur[256];
    int t = threadIdx.x, b = blockIdx.x;
    if (t < nbk) cur[t] = off[t * NBLK + b];
    __syncthreads();
    int est = b * epb;
    int een = min(E, est + epb);
    for (int e = est + t; e < een; e += 512) {
        int s = ei[e], d = ei[E + e];
        float4 a0 = *(const float4*)(ea + (size_t)e * 8);
        float4 a1 = *(const float4*)(ea + (size_t)e * 8 + 4);
        uint4 at;
        at.x = pack2f(a0.x, a0.y); at.y = pack2f(a0.z, a0.w);
        at.z = pack2f(a1.x, a1.y); at.w = pack2f(a1.z, a1.w);
        int p = atomicAdd(&cur[s >> NSH], 1);
        p1sd[p] = make_int2(s, d);
        p1at[p] = at;
    }
}

// ===========================================================================
// Pass D: per-bucket node-level counting sort.  One block per bucket; the
// bucket's record region (~200 KB) is L2/L3-resident, so the scattered final
// stores RMW in cache instead of at the memory side.
// ===========================================================================
__global__ __launch_bounds__(512) void bucket_csr(
    const int2* __restrict__ p1sd, const uint4* __restrict__ p1at,
    const int* __restrict__ off,
    int2* __restrict__ rsd, uint4* __restrict__ rat,
    int E, int nbk)
{
    __shared__ int h[512];
    __shared__ int cur[512];
    int t = threadIdx.x, k = blockIdx.x;
    int base = off[k * NBLK];
    int end = (k + 1 < nbk) ? off[(k + 1) * NBLK] : E;
    int n0 = k << NSH;
    h[t] = 0;
    __syncthreads();
    for (int p = base + t; p < end; p += 512)
        atomicAdd(&h[p1sd[p].x - n0], 1);
    __syncthreads();
    // inclusive scan over 512 (Hillis-Steele)
    for (int o = 1; o < 512; o <<= 1) {
        int v = (t >= o) ? h[t - o] : 0;
        __syncthreads();
        h[t] += v;
        __syncthreads();
    }
    cur[t] = base + (t ? h[t - 1] : 0);
    __syncthreads();
    for (int p = base + t; p < end; p += 512) {
        int2 sd = p1sd[p];
        uint4 at = p1at[p];
        int q = atomicAdd(&cur[sd.x - n0], 1);
        rsd[q] = sd;
        rat[q] = at;
    }
}

// ===========================================================================
// conv1 edge-MLP + FUSED segmented max (unchanged structure from round 10;
// rec is now SoA so attr loads are single aligned 16 B).
//   16x16x32 layouts: A[m=lane&15][k=8q+j], B[k=8q+j][n=lane&15],
//   C/D: col=lane&15, row=4q+reg.
// ===========================================================================
__global__ __launch_bounds__(256) void edge_mlp1_agg(
    const _Float16* __restrict__ xh,      // [N,4] fp16
    const int2*  __restrict__ rsd,        // [E] CSR (src,dst)
    const uint4* __restrict__ rat,        // [E] CSR attr fp16x8
    const float* __restrict__ w1, const float* __restrict__ b1,  // 16x16
    const float* __restrict__ w2, const float* __restrict__ b2,  // 16x16
    int* __restrict__ aggi,               // [N,16] f32-bits, memset 0
    int E)
{
    __shared__ _Float16 itm[4][8][16][24];
    __shared__ int lmax[SPAN * 16];
    int tid = threadIdx.x;
    int w = tid >> 6, lane = tid & 63;
    int e16 = lane & 15, q = lane >> 4;
    int kb = blockIdx.x * 512;
    int ebase = kb + (w << 7);            // 128 edges per wave
    int e0 = ebase + lane;
    int e1 = ebase + 64 + lane;

    #pragma unroll
    for (int i = 0; i < SPAN * 16 / 256; ++i) lmax[tid + i * 256] = 0;

    int klast = min(kb + 511, E - 1);
    int n_first = rsd[kb].x;
    int n_last  = rsd[klast].x;
    int span = n_last - n_first + 1;
    bool fb = (span > SPAN);
    __syncthreads();

    int s0 = 0, d0 = 0, s1 = 0, d1 = 0;
    if (e0 < E) { int2 p = rsd[e0]; s0 = p.x; d0 = p.y; }
    if (e1 < E) { int2 p = rsd[e1]; s1 = p.x; d1 = p.y; }

    half8 B1, B2;
    #pragma unroll
    for (int j = 0; j < 8; ++j) { B1[j] = (_Float16)0.f; B2[j] = (_Float16)0.f; }
    if (q < 2) {
        #pragma unroll
        for (int j = 0; j < 8; ++j) {
            B1[j] = (_Float16)w1[(8 * q + j) * 16 + e16];
            B2[j] = (_Float16)w2[(8 * q + j) * 16 + e16];
        }
    }
    float b1c = b1[e16], b2c = b2[e16];

    half8 A[8];
    #pragma unroll
    for (int t = 0; t < 8; ++t) {
        int tt = t & 3;
        int st = (t < 4) ? __shfl(s0, 16 * tt + e16, 64) : __shfl(s1, 16 * tt + e16, 64);
        int dt = (t < 4) ? __shfl(d0, 16 * tt + e16, 64) : __shfl(d1, 16 * tt + e16, 64);
        half8 a;
        #pragma unroll
        for (int j = 0; j < 8; ++j) a[j] = (_Float16)0.f;
        int et = ebase + 16 * t + e16;
        if (q == 0 && et < E) {
            half4 hs = *(const half4*)(xh + (size_t)st * 4);
            half4 hd = *(const half4*)(xh + (size_t)dt * 4);
            a[0] = hs[0]; a[1] = hs[1]; a[2] = hs[2]; a[3] = hs[3];
            a[4] = hd[0]; a[5] = hd[1]; a[6] = hd[2]; a[7] = hd[3];
        } else if (q == 1 && et < E) {
            a = load_attr(rat, et);
        }
        A[t] = a;
    }

    floatx4 C[8];
    #pragma unroll
    for (int t = 0; t < 8; ++t) {
        floatx4 c = {b1c, b1c, b1c, b1c};
        C[t] = __builtin_amdgcn_mfma_f32_16x16x32_f16(A[t], B1, c, 0, 0, 0);
    }
    #pragma unroll
    for (int t = 0; t < 8; ++t)
        #pragma unroll
        for (int i = 0; i < 4; ++i)
            itm[w][t][4 * q + i][e16] = (_Float16)fmaxf(C[t][i], 0.0f);
    __builtin_amdgcn_wave_barrier();

    half8 A2[8];
    #pragma unroll
    for (int t = 0; t < 8; ++t) {
        half8 a;
        #pragma unroll
        for (int j = 0; j < 8; ++j) a[j] = (_Float16)0.f;
        if (q < 2) a = *(const half8*)&itm[w][t][e16][8 * q];
        A2[t] = a;
    }
    __builtin_amdgcn_wave_barrier();
    floatx4 C2[8];
    #pragma unroll
    for (int t = 0; t < 8; ++t) {
        floatx4 c = {b2c, b2c, b2c, b2c};
        C2[t] = __builtin_amdgcn_mfma_f32_16x16x32_f16(A2[t], B2, c, 0, 0, 0);
    }

    // fused segmented max
    #pragma unroll
    for (int t = 0; t < 8; ++t) {
        int tt = t & 3;
        #pragma unroll
        for (int i = 0; i < 4; ++i) {
            int rr = 4 * q + i;
            int nn = (t < 4) ? __shfl(s0, 16 * tt + rr, 64) : __shfl(s1, 16 * tt + rr, 64);
            int et = ebase + 16 * t + rr;
            if (et < E) {
                int bits = __float_as_int(fmaxf(C2[t][i], 0.0f));
                if (!fb) atomicMax(&lmax[(nn - n_first) * 16 + e16], bits);
                else     atomicMax(&aggi[(size_t)nn * 16 + e16], bits);
            }
        }
    }
    __syncthreads();
    if (!fb) {
        int tot = span * 16;
        for (int idx = tid; idx < tot; idx += 256) {
            int row = idx >> 4;
            int nn = n_first + row;
            int v = lmax[idx];
            if (nn == n_first || nn == n_last) {
                if (v != 0) atomicMax(&aggi[(size_t)nn * 16 + (idx & 15)], v);
            } else {
                aggi[(size_t)nn * 16 + (idx & 15)] = v;
            }
        }
    }
}

// agg1 (f32 bits) -> h1 fp16, packed pairs
__global__ __launch_bounds__(256) void cvt_h1(
    const int* __restrict__ aggi, unsigned int* __restrict__ h1u, int total)
{
    int i = blockIdx.x * 256 + threadIdx.x;
    if (i >= total) return;
    int2 v = *(const int2*)(aggi + 2 * i);
    h1u[i] = pack2f(__int_as_float(v.x), __int_as_float(v.y));
}

// ===========================================================================
// conv2 edge-MLP + fused segmented max (structure unchanged; SoA rec).
// ===========================================================================
__global__ __launch_bounds__(256) void edge_mlp2_agg(
    const _Float16* __restrict__ h1,           // [N,16] fp16
    const int2*  __restrict__ rsd,
    const uint4* __restrict__ rat,
    const float* __restrict__ w1, const float* __restrict__ b1v, // [40,16],[16]
    const float* __restrict__ w2, const float* __restrict__ b2,  // 16x16
    int* __restrict__ aggi, int E)
{
    __shared__ _Float16 itm[4][8][16][24];
    __shared__ int lmax[SPAN * 16];
    int tid = threadIdx.x;
    int w = tid >> 6, lane = tid & 63;
    int e16 = lane & 15, q = lane >> 4;
    int kb = blockIdx.x * 512;
    int ebase = kb + (w << 7);
    int e0 = ebase + lane;
    int e1 = ebase + 64 + lane;

    #pragma unroll
    for (int i = 0; i < SPAN * 16 / 256; ++i) lmax[tid + i * 256] = 0;

    int klast = min(kb + 511, E - 1);
    int n_first = rsd[kb].x;
    int n_last  = rsd[klast].x;
    int span = n_last - n_first + 1;
    bool fb = (span > SPAN);
    __syncthreads();

    int s0 = 0, d0 = 0, s1 = 0, d1 = 0;
    if (e0 < E) { int2 p = rsd[e0]; s0 = p.x; d0 = p.y; }
    if (e1 < E) { int2 p = rsd[e1]; s1 = p.x; d1 = p.y; }

    half8 B1, B2e, BL2;
    #pragma unroll
    for (int j = 0; j < 8; ++j) {
        B1[j] = (_Float16)w1[(8 * q + j) * 16 + e16];
        B2e[j] = (_Float16)0.f; BL2[j] = (_Float16)0.f;
    }
    if (q == 0) {
        #pragma unroll
        for (int j = 0; j < 8; ++j)
            B2e[j] = (_Float16)w1[(32 + j) * 16 + e16];
    }
    if (q < 2) {
        #pragma unroll
        for (int j = 0; j < 8; ++j)
            BL2[j] = (_Float16)w2[(8 * q + j) * 16 + e16];
    }
    float b1c = b1v[e16], b2c = b2[e16];

    half8 A1[8];
    #pragma unroll
    for (int t = 0; t < 8; ++t) {
        int tt = t & 3;
        int st = (t < 4) ? __shfl(s0, 16 * tt + e16, 64) : __shfl(s1, 16 * tt + e16, 64);
        int dt = (t < 4) ? __shfl(d0, 16 * tt + e16, 64) : __shfl(d1, 16 * tt + e16, 64);
        int row = (q < 2) ? st : dt;
        A1[t] = *(const half8*)(h1 + (size_t)row * 16 + 8 * (q & 1));
    }

    floatx4 C[8];
    #pragma unroll
    for (int t = 0; t < 8; ++t) {
        half8 a2;
        #pragma unroll
        for (int j = 0; j < 8; ++j) a2[j] = (_Float16)0.f;
        int et = ebase + 16 * t + e16;
        if (q == 0 && et < E)
            a2 = load_attr(rat, et);
        floatx4 c = {b1c, b1c, b1c, b1c};
        c = __builtin_amdgcn_mfma_f32_16x16x32_f16(a2, B2e, c, 0, 0, 0);
        C[t] = __builtin_amdgcn_mfma_f32_16x16x32_f16(A1[t], B1, c, 0, 0, 0);
    }
    #pragma unroll
    for (int t = 0; t < 8; ++t)
        #pragma unroll
        for (int i = 0; i < 4; ++i)
            itm[w][t][4 * q + i][e16] = (_Float16)fmaxf(C[t][i], 0.0f);
    __builtin_amdgcn_wave_barrier();

    half8 A2L[8];
    #pragma unroll
    for (int t = 0; t < 8; ++t) {
        half8 a;
        #pragma unroll
        for (int j = 0; j < 8; ++j) a[j] = (_Float16)0.f;
        if (q < 2) a = *(const half8*)&itm[w][t][e16][8 * q];
        A2L[t] = a;
    }
    __builtin_amdgcn_wave_barrier();
    floatx4 C2[8];
    #pragma unroll
    for (int t = 0; t < 8; ++t) {
        floatx4 c = {b2c, b2c, b2c, b2c};
        C2[t] = __builtin_amdgcn_mfma_f32_16x16x32_f16(A2L[t], BL2, c, 0, 0, 0);
    }

    #pragma unroll
    for (int t = 0; t < 8; ++t) {
        int tt = t & 3;
        #pragma unroll
        for (int i = 0; i < 4; ++i) {
            int rr = 4 * q + i;
            int nn = (t < 4) ? __shfl(s0, 16 * tt + rr, 64) : __shfl(s1, 16 * tt + rr, 64);
            int et = ebase + 16 * t + rr;
            if (et < E) {
                int bits = __float_as_int(fmaxf(C2[t][i], 0.0f));
                if (!fb) atomicMax(&lmax[(nn - n_first) * 16 + e16], bits);
                else     atomicMax(&aggi[(size_t)nn * 16 + e16], bits);
            }
        }
    }
    __syncthreads();
    if (!fb) {
        int tot = span * 16;
        for (int idx = tid; idx < tot; idx += 256) {
            int row = idx >> 4;
            int nn = n_first + row;
            int v = lmax[idx];
            if (nn == n_first || nn == n_last) {
                if (v != 0) atomicMax(&aggi[(size_t)nn * 16 + (idx & 15)], v);
            } else {
                aggi[(size_t)nn * 16 + (idx & 15)] = v;
            }
        }
    }
}

// ===========================================================================
// Dense per-node head: h2 -> relu(h2@l1+b) @ l2 + b
// ===========================================================================
__global__ __launch_bounds__(256) void head_out(
    const int* __restrict__ aggi,
    const float* __restrict__ l1w, const float* __restrict__ l1b,
    const float* __restrict__ l2w, const float* __restrict__ l2b,
    float* __restrict__ out, int N)
{
    int n = blockIdx.x * 256 + threadIdx.x;
    if (n >= N) return;
    const float4* ar = (const float4*)(aggi + (size_t)n * 16);
    float4 A0 = ar[0], A1 = ar[1], A2 = ar[2], A3 = ar[3];
    float acc[16] = {A0.x, A0.y, A0.z, A0.w, A1.x, A1.y, A1.z, A1.w,
                     A2.x, A2.y, A2.z, A2.w, A3.x, A3.y, A3.z, A3.w};
    float t2[16];
    #pragma unroll
    for (int j = 0; j < 16; ++j) t2[j] = l1b[j];
    #pragma unroll
    for (int k = 0; k < 16; ++k) {
        float ak = acc[k];
        #pragma unroll
        for (int j = 0; j < 16; ++j) t2[j] = fmaf(ak, l1w[k * 16 + j], t2[j]);
    }
    float r2 = l2b[0];
    #pragma unroll
    for (int j = 0; j < 16; ++j) r2 = fmaf(fmaxf(t2[j], 0.0f), l2w[j], r2);
    out[n] = r2;
}

// ===========================================================================
extern "C" void kernel_launch(void* const* d_in, const int* in_sizes, int n_in,
                              void* d_out, int out_size, void* d_ws, size_t ws_size,
                              hipStream_t stream)
{
    const float* x     = (const float*)d_in[0];
    const int*   ei    = (const int*)  d_in[1];
    const float* ea    = (const float*)d_in[2];
    const float* c1_w1 = (const float*)d_in[3];
    const float* c1_b1 = (const float*)d_in[4];
    const float* c1_w2 = (const float*)d_in[5];
    const float* c1_b2 = (const float*)d_in[6];
    const float* c2_w1 = (const float*)d_in[7];
    const float* c2_b1 = (const float*)d_in[8];
    const float* c2_w2 = (const float*)d_in[9];
    const float* c2_b2 = (const float*)d_in[10];
    const float* l1_w  = (const float*)d_in[11];
    const float* l1_b  = (const float*)d_in[12];
    const float* l2_w  = (const float*)d_in[13];
    const float* l2_b  = (const float*)d_in[14];
    float* out = (float*)d_out;

    const int N = in_sizes[0] / 4;   // 100000
    const int E = in_sizes[2] / 8;   // 1600000
    const int nbk = (N + (1 << NSH) - 1) >> NSH;   // 196 buckets
    const int epb = (E + NBLK - 1) / NBLK;         // edges per hist/part block
    const int ntot = nbk * NBLK;                   // 50176 count entries
    const int nch = (ntot + CHUNK - 1) / CHUNK;    // 49

    const int BLK = 256;
    const int mgrid = (E + 511) / 512;     // 512 CSR edges per block
    const int ngrid = (N + 255) / 256;
    const int cgrid = (N * 8 + 255) / 256; // cvt_h1: N*16/2 words

    size_t szXh  = ((size_t)N * 8 + 255) & ~(size_t)255;    // 0.8 MB
    size_t szH1  = ((size_t)N * 32 + 255) & ~(size_t)255;   // 3.2 MB
    size_t szSd  = ((size_t)E * 8 + 255) & ~(size_t)255;    // 12.8 MB
    size_t szAt  = ((size_t)E * 16 + 255) & ~(size_t)255;   // 25.6 MB
    size_t szCnt = ((size_t)ntot * 4 + 255) & ~(size_t)255; // 0.2 MB
    size_t szAgg = ((size_t)N * 64 + 255) & ~(size_t)255;   // 6.4 MB

    size_t xh_off   = 0;
    size_t h1_off   = xh_off   + szXh;
    size_t rsd_off  = h1_off   + szH1;
    size_t rat_off  = rsd_off  + szSd;
    size_t p1sd_off = rat_off  + szAt;
    size_t p1at_off = p1sd_off + szSd;
    size_t cnt_off  = p1at_off + szAt;
    size_t off_off  = cnt_off  + szCnt;
    size_t cs_off   = off_off  + szCnt;
    size_t cf_off   = cs_off   + 4096;
    // agg arrays overlay P1 (dead after bucket_csr)
    size_t agg1_off = p1sd_off;
    size_t agg2_off = p1sd_off + szAgg;

    _Float16* xh   = (_Float16*)((char*)d_ws + xh_off);
    _Float16* h1   = (_Float16*)((char*)d_ws + h1_off);
    int2*     rsd  = (int2*)    ((char*)d_ws + rsd_off);
    uint4*    rat  = (uint4*)   ((char*)d_ws + rat_off);
    int2*     p1sd = (int2*)    ((char*)d_ws + p1sd_off);
    uint4*    p1at = (uint4*)   ((char*)d_ws + p1at_off);
    int*      cnt  = (int*)     ((char*)d_ws + cnt_off);
    int*      off  = (int*)     ((char*)d_ws + off_off);
    int*      csum = (int*)     ((char*)d_ws + cs_off);
    int*      coff = (int*)     ((char*)d_ws + cf_off);
    int*      agg1 = (int*)     ((char*)d_ws + agg1_off);
    int*      agg2 = (int*)     ((char*)d_ws + agg2_off);

    hist_x<<<NBLK, 512, 0, stream>>>(ei, x, cnt, xh, E, N, nbk, epb);
    scan_chunk_sums<<<nch, BLK, 0, stream>>>(cnt, csum, ntot);
    scan_chunk_off<<<1, 256, 0, stream>>>(csum, coff, nch);
    scan_within_excl<<<nch, BLK, 0, stream>>>(cnt, off, coff, ntot);
    partition<<<NBLK, 512, 0, stream>>>(ei, ea, off, p1sd, p1at, E, nbk, epb);
    bucket_csr<<<nbk, 512, 0, stream>>>(p1sd, p1at, off, rsd, rat, E, nbk);
    // P1 dead; agg arrays overlay it
    hipMemsetAsync(agg1, 0, (size_t)N * 64, stream);
    hipMemsetAsync(agg2, 0, (size_t)N * 64, stream);
    edge_mlp1_agg<<<mgrid, BLK, 0, stream>>>(xh, rsd, rat,
                                             c1_w1, c1_b1, c1_w2, c1_b2,
                                             agg1, E);
    cvt_h1<<<cgrid, BLK, 0, stream>>>(agg1, (unsigned int*)h1, N * 8);
    edge_mlp2_agg<<<mgrid, BLK, 0, stream>>>(h1, rsd, rat,
                                             c2_w1, c2_b1, c2_w2, c2_b2,
                                             agg2, E);
    head_out<<<ngrid, BLK, 0, stream>>>(agg2, l1_w, l1_b, l2_w, l2_b, out, N);
}

// Round 13
// 300.523 us; speedup vs baseline: 1.2072x; 1.0104x over previous
//
#include <hip/hip_runtime.h>
#include <hip/hip_fp16.h>

#define CHUNK 1024
#define NBLK 1024  // blocks in hist/partition passes (full-device grid)
#define NSH  9     // nodes per bucket = 512
#define SPAN 192   // max node-span of a 512-edge CSR block handled in LDS

typedef _Float16 half8 __attribute__((ext_vector_type(8)));
typedef _Float16 half4 __attribute__((ext_vector_type(4)));
typedef float floatx4 __attribute__((ext_vector_type(4)));

__device__ __forceinline__ unsigned int pack2f(float a, float b) {
    __half2 h = __floats2half2_rn(a, b);
    return *(unsigned int*)&h;
}

__device__ __forceinline__ half8 load_attr(const uint4* __restrict__ rat, int et) {
    union { uint4 u; half8 h; } cv;
    cv.u = rat[et];
    return cv.h;
}

// ===========================================================================
// Pass A: per-block LDS bucket histogram (bucket = src>>9, 196 buckets) +
// x -> fp16.  cnt is [bucket][NBLK] so one flat exclusive scan yields every
// (block,bucket) run base directly.
// ===========================================================================
__global__ __launch_bounds__(512) void hist_x(
    const int* __restrict__ ei, const float* __restrict__ x,
    int* __restrict__ cnt, _Float16* __restrict__ xh,
    int E, int N, int nbk, int epb)
{
    __shared__ int h[256];
    int t = threadIdx.x, b = blockIdx.x;
    if (t < 256) h[t] = 0;
    __syncthreads();
    int est = b * epb;
    int een = min(E, est + epb);
    for (int e = est + t; e < een; e += 512)
        atomicAdd(&h[ei[e] >> NSH], 1);
    for (int i = est + t; i < een; i += 512)
        if (i < N) {
            float4 xv = *(const float4*)(x + (size_t)i * 4);
            half4 hx;
            hx[0] = (_Float16)xv.x; hx[1] = (_Float16)xv.y;
            hx[2] = (_Float16)xv.z; hx[3] = (_Float16)xv.w;
            *(half4*)(xh + (size_t)i * 4) = hx;
        }
    __syncthreads();
    if (t < nbk) cnt[t * NBLK + b] = h[t];
}

__global__ __launch_bounds__(256) void scan_chunk_sums(
    const int* __restrict__ v, int* __restrict__ csum, int N)
{
    __shared__ int s[256];
    int base = blockIdx.x * CHUNK;
    int t = threadIdx.x;
    int acc = 0;
    #pragma unroll
    for (int i = 0; i < CHUNK / 256; ++i) {
        int idx = base + t + i * 256;
        if (idx < N) acc += v[idx];
    }
    s[t] = acc; __syncthreads();
    for (int o = 128; o > 0; o >>= 1) {
        if (t < o) s[t] += s[t + o];
        __syncthreads();
    }
    if (t == 0) csum[blockIdx.x] = s[0];
}

__global__ __launch_bounds__(256) void scan_chunk_off(
    const int* __restrict__ csum, int* __restrict__ coff, int nch)
{
    __shared__ int s[256];
    __shared__ int carry;
    int t = threadIdx.x;
    if (t == 0) carry = 0;
    __syncthreads();
    for (int base = 0; base < nch; base += 256) {
        int v = (base + t < nch) ? csum[base + t] : 0;
        s[t] = v; __syncthreads();
        for (int o = 1; o < 256; o <<= 1) {
            int add = (t >= o) ? s[t - o] : 0;
            __syncthreads();
            s[t] += add;
            __syncthreads();
        }
        int excl = carry + (t > 0 ? s[t - 1] : 0);
        if (base + t < nch) coff[base + t] = excl;
        __syncthreads();
        if (t == 0) carry += s[255];
        __syncthreads();
    }
}

__global__ __launch_bounds__(256) void scan_within_excl(
    const int* __restrict__ deg, int* __restrict__ pos,
    const int* __restrict__ coff, int N)
{
    __shared__ int s[256];
    int t = threadIdx.x;
    int base = blockIdx.x * CHUNK + t * 4;
    int v0 = 0, v1 = 0, v2 = 0, v3 = 0;
    if (base + 0 < N) v0 = deg[base + 0];
    if (base + 1 < N) v1 = deg[base + 1];
    if (base + 2 < N) v2 = deg[base + 2];
    if (base + 3 < N) v3 = deg[base + 3];
    s[t] = v0 + v1 + v2 + v3;
    __syncthreads();
    for (int o = 1; o < 256; o <<= 1) {
        int add = (t >= o) ? s[t - o] : 0;
        __syncthreads();
        s[t] += add;
        __syncthreads();
    }
    int run = coff[blockIdx.x] + (t > 0 ? s[t - 1] : 0);
    if (base + 0 < N) pos[base + 0] = run; run += v0;
    if (base + 1 < N) pos[base + 1] = run; run += v1;
    if (base + 2 < N) pos[base + 2] = run; run += v2;
    if (base + 3 < N) pos[base + 3] = run;
}

// ===========================================================================
// Pass C: partition edges into bucket-major order.  LDS cursors (no global
// atomics); each (block,bucket) run is ~8 contiguous edges -> short burst
// writes.  SoA: sd int2 + at uint4.
// ===========================================================================
__global__ __launch_bounds__(512) void partition(
    const int* __restrict__ ei, const float* __restrict__ ea,
    const int* __restrict__ off,
    int2* __restrict__ p1sd, uint4* __restrict__ p1at,
    int E, int nbk, int epb)
{
    __shared__ int cur[256];
    int t = threadIdx.x, b = blockIdx.x;
    if (t < nbk) cur[t] = off[t * NBLK + b];
    __syncthreads();
    int est = b * epb;
    int een = min(E, est + epb);
    for (int e = est + t; e < een; e += 512) {
        int s = ei[e], d = ei[E + e];
        float4 a0 = *(const float4*)(ea + (size_t)e * 8);
        float4 a1 = *(const float4*)(ea + (size_t)e * 8 + 4);
        uint4 at;
        at.x = pack2f(a0.x, a0.y); at.y = pack2f(a0.z, a0.w);
        at.z = pack2f(a1.x, a1.y); at.w = pack2f(a1.z, a1.w);
        int p = atomicAdd(&cur[s >> NSH], 1);
        p1sd[p] = make_int2(s, d);
        p1at[p] = at;
    }
}

// ===========================================================================
// Pass D: per-bucket node-level counting sort.  One 1024-thread block per
// bucket; the bucket's record region (~200 KB) is L2/L3-resident, so the
// scattered final stores RMW in cache instead of at the memory side.
// ===========================================================================
__global__ __launch_bounds__(1024) void bucket_csr(
    const int2* __restrict__ p1sd, const uint4* __restrict__ p1at,
    const int* __restrict__ off,
    int2* __restrict__ rsd, uint4* __restrict__ rat,
    int E, int nbk)
{
    __shared__ int h[512];
    __shared__ int cur[512];
    int t = threadIdx.x, k = blockIdx.x;
    int base = off[k * NBLK];
    int end = (k + 1 < nbk) ? off[(k + 1) * NBLK] : E;
    int n0 = k << NSH;
    if (t < 512) h[t] = 0;
    __syncthreads();
    for (int p = base + t; p < end; p += 1024)
        atomicAdd(&h[p1sd[p].x - n0], 1);
    __syncthreads();
    // inclusive scan over 512 (Hillis-Steele; threads >=512 just barrier)
    for (int o = 1; o < 512; o <<= 1) {
        int v = (t >= o && t < 512) ? h[t - o] : 0;
        __syncthreads();
        if (t < 512) h[t] += v;
        __syncthreads();
    }
    if (t < 512) cur[t] = base + (t ? h[t - 1] : 0);
    __syncthreads();
    for (int p = base + t; p < end; p += 1024) {
        int2 sd = p1sd[p];
        uint4 at = p1at[p];
        int q = atomicAdd(&cur[sd.x - n0], 1);
        rsd[q] = sd;
        rat[q] = at;
    }
}

// ===========================================================================
// conv1 edge-MLP + FUSED segmented max.
//   16x16x32 layouts: A[m=lane&15][k=8q+j], B[k=8q+j][n=lane&15],
//   C/D: col=lane&15, row=4q+reg.
// ===========================================================================
__global__ __launch_bounds__(256) void edge_mlp1_agg(
    const _Float16* __restrict__ xh,      // [N,4] fp16
    const int2*  __restrict__ rsd,        // [E] CSR (src,dst)
    const uint4* __restrict__ rat,        // [E] CSR attr fp16x8
    const float* __restrict__ w1, const float* __restrict__ b1,  // 16x16
    const float* __restrict__ w2, const float* __restrict__ b2,  // 16x16
    int* __restrict__ aggi,               // [N,16] f32-bits, memset 0
    int E)
{
    __shared__ _Float16 itm[4][8][16][24];
    __shared__ int lmax[SPAN * 16];
    int tid = threadIdx.x;
    int w = tid >> 6, lane = tid & 63;
    int e16 = lane & 15, q = lane >> 4;
    int kb = blockIdx.x * 512;
    int ebase = kb + (w << 7);            // 128 edges per wave
    int e0 = ebase + lane;
    int e1 = ebase + 64 + lane;

    #pragma unroll
    for (int i = 0; i < SPAN * 16 / 256; ++i) lmax[tid + i * 256] = 0;

    int klast = min(kb + 511, E - 1);
    int n_first = rsd[kb].x;
    int n_last  = rsd[klast].x;
    int span = n_last - n_first + 1;
    bool fb = (span > SPAN);
    __syncthreads();

    int s0 = 0, d0 = 0, s1 = 0, d1 = 0;
    if (e0 < E) { int2 p = rsd[e0]; s0 = p.x; d0 = p.y; }
    if (e1 < E) { int2 p = rsd[e1]; s1 = p.x; d1 = p.y; }

    half8 B1, B2;
    #pragma unroll
    for (int j = 0; j < 8; ++j) { B1[j] = (_Float16)0.f; B2[j] = (_Float16)0.f; }
    if (q < 2) {
        #pragma unroll
        for (int j = 0; j < 8; ++j) {
            B1[j] = (_Float16)w1[(8 * q + j) * 16 + e16];
            B2[j] = (_Float16)w2[(8 * q + j) * 16 + e16];
        }
    }
    float b1c = b1[e16], b2c = b2[e16];

    half8 A[8];
    #pragma unroll
    for (int t = 0; t < 8; ++t) {
        int tt = t & 3;
        int st = (t < 4) ? __shfl(s0, 16 * tt + e16, 64) : __shfl(s1, 16 * tt + e16, 64);
        int dt = (t < 4) ? __shfl(d0, 16 * tt + e16, 64) : __shfl(d1, 16 * tt + e16, 64);
        half8 a;
        #pragma unroll
        for (int j = 0; j < 8; ++j) a[j] = (_Float16)0.f;
        int et = ebase + 16 * t + e16;
        if (q == 0 && et < E) {
            half4 hs = *(const half4*)(xh + (size_t)st * 4);
            half4 hd = *(const half4*)(xh + (size_t)dt * 4);
            a[0] = hs[0]; a[1] = hs[1]; a[2] = hs[2]; a[3] = hs[3];
            a[4] = hd[0]; a[5] = hd[1]; a[6] = hd[2]; a[7] = hd[3];
        } else if (q == 1 && et < E) {
            a = load_attr(rat, et);
        }
        A[t] = a;
    }

    floatx4 C[8];
    #pragma unroll
    for (int t = 0; t < 8; ++t) {
        floatx4 c = {b1c, b1c, b1c, b1c};
        C[t] = __builtin_amdgcn_mfma_f32_16x16x32_f16(A[t], B1, c, 0, 0, 0);
    }
    #pragma unroll
    for (int t = 0; t < 8; ++t)
        #pragma unroll
        for (int i = 0; i < 4; ++i)
            itm[w][t][4 * q + i][e16] = (_Float16)fmaxf(C[t][i], 0.0f);
    __builtin_amdgcn_wave_barrier();

    half8 A2[8];
    #pragma unroll
    for (int t = 0; t < 8; ++t) {
        half8 a;
        #pragma unroll
        for (int j = 0; j < 8; ++j) a[j] = (_Float16)0.f;
        if (q < 2) a = *(const half8*)&itm[w][t][e16][8 * q];
        A2[t] = a;
    }
    __builtin_amdgcn_wave_barrier();
    floatx4 C2[8];
    #pragma unroll
    for (int t = 0; t < 8; ++t) {
        floatx4 c = {b2c, b2c, b2c, b2c};
        C2[t] = __builtin_amdgcn_mfma_f32_16x16x32_f16(A2[t], B2, c, 0, 0, 0);
    }

    // fused segmented max
    #pragma unroll
    for (int t = 0; t < 8; ++t) {
        int tt = t & 3;
        #pragma unroll
        for (int i = 0; i < 4; ++i) {
            int rr = 4 * q + i;
            int nn = (t < 4) ? __shfl(s0, 16 * tt + rr, 64) : __shfl(s1, 16 * tt + rr, 64);
            int et = ebase + 16 * t + rr;
            if (et < E) {
                int bits = __float_as_int(fmaxf(C2[t][i], 0.0f));
                if (!fb) atomicMax(&lmax[(nn - n_first) * 16 + e16], bits);
                else     atomicMax(&aggi[(size_t)nn * 16 + e16], bits);
            }
        }
    }
    __syncthreads();
    if (!fb) {
        int tot = span * 16;
        for (int idx = tid; idx < tot; idx += 256) {
            int row = idx >> 4;
            int nn = n_first + row;
            int v = lmax[idx];
            if (nn == n_first || nn == n_last) {
                if (v != 0) atomicMax(&aggi[(size_t)nn * 16 + (idx & 15)], v);
            } else {
                aggi[(size_t)nn * 16 + (idx & 15)] = v;
            }
        }
    }
}

// agg1 (f32 bits) -> h1 fp16, packed pairs
__global__ __launch_bounds__(256) void cvt_h1(
    const int* __restrict__ aggi, unsigned int* __restrict__ h1u, int total)
{
    int i = blockIdx.x * 256 + threadIdx.x;
    if (i >= total) return;
    int2 v = *(const int2*)(aggi + 2 * i);
    h1u[i] = pack2f(__int_as_float(v.x), __int_as_float(v.y));
}

// ===========================================================================
// conv2 edge-MLP + fused segmented max.
// ===========================================================================
__global__ __launch_bounds__(256) void edge_mlp2_agg(
    const _Float16* __restrict__ h1,           // [N,16] fp16
    const int2*  __restrict__ rsd,
    const uint4* __restrict__ rat,
    const float* __restrict__ w1, const float* __restrict__ b1v, // [40,16],[16]
    const float* __restrict__ w2, const float* __restrict__ b2,  // 16x16
    int* __restrict__ aggi, int E)
{
    __shared__ _Float16 itm[4][8][16][24];
    __shared__ int lmax[SPAN * 16];
    int tid = threadIdx.x;
    int w = tid >> 6, lane = tid & 63;
    int e16 = lane & 15, q = lane >> 4;
    int kb = blockIdx.x * 512;
    int ebase = kb + (w << 7);
    int e0 = ebase + lane;
    int e1 = ebase + 64 + lane;

    #pragma unroll
    for (int i = 0; i < SPAN * 16 / 256; ++i) lmax[tid + i * 256] = 0;

    int klast = min(kb + 511, E - 1);
    int n_first = rsd[kb].x;
    int n_last  = rsd[klast].x;
    int span = n_last - n_first + 1;
    bool fb = (span > SPAN);
    __syncthreads();

    int s0 = 0, d0 = 0, s1 = 0, d1 = 0;
    if (e0 < E) { int2 p = rsd[e0]; s0 = p.x; d0 = p.y; }
    if (e1 < E) { int2 p = rsd[e1]; s1 = p.x; d1 = p.y; }

    half8 B1, B2e, BL2;
    #pragma unroll
    for (int j = 0; j < 8; ++j) {
        B1[j] = (_Float16)w1[(8 * q + j) * 16 + e16];
        B2e[j] = (_Float16)0.f; BL2[j] = (_Float16)0.f;
    }
    if (q == 0) {
        #pragma unroll
        for (int j = 0; j < 8; ++j)
            B2e[j] = (_Float16)w1[(32 + j) * 16 + e16];
    }
    if (q < 2) {
        #pragma unroll
        for (int j = 0; j < 8; ++j)
            BL2[j] = (_Float16)w2[(8 * q + j) * 16 + e16];
    }
    float b1c = b1v[e16], b2c = b2[e16];

    half8 A1[8];
    #pragma unroll
    for (int t = 0; t < 8; ++t) {
        int tt = t & 3;
        int st = (t < 4) ? __shfl(s0, 16 * tt + e16, 64) : __shfl(s1, 16 * tt + e16, 64);
        int dt = (t < 4) ? __shfl(d0, 16 * tt + e16, 64) : __shfl(d1, 16 * tt + e16, 64);
        int row = (q < 2) ? st : dt;
        A1[t] = *(const half8*)(h1 + (size_t)row * 16 + 8 * (q & 1));
    }

    floatx4 C[8];
    #pragma unroll
    for (int t = 0; t < 8; ++t) {
        half8 a2;
        #pragma unroll
        for (int j = 0; j < 8; ++j) a2[j] = (_Float16)0.f;
        int et = ebase + 16 * t + e16;
        if (q == 0 && et < E)
            a2 = load_attr(rat, et);
        floatx4 c = {b1c, b1c, b1c, b1c};
        c = __builtin_amdgcn_mfma_f32_16x16x32_f16(a2, B2e, c, 0, 0, 0);
        C[t] = __builtin_amdgcn_mfma_f32_16x16x32_f16(A1[t], B1, c, 0, 0, 0);
    }
    #pragma unroll
    for (int t = 0; t < 8; ++t)
        #pragma unroll
        for (int i = 0; i < 4; ++i)
            itm[w][t][4 * q + i][e16] = (_Float16)fmaxf(C[t][i], 0.0f);
    __builtin_amdgcn_wave_barrier();

    half8 A2L[8];
    #pragma unroll
    for (int t = 0; t < 8; ++t) {
        half8 a;
        #pragma unroll
        for (int j = 0; j < 8; ++j) a[j] = (_Float16)0.f;
        if (q < 2) a = *(const half8*)&itm[w][t][e16][8 * q];
        A2L[t] = a;
    }
    __builtin_amdgcn_wave_barrier();
    floatx4 C2[8];
    #pragma unroll
    for (int t = 0; t < 8; ++t) {
        floatx4 c = {b2c, b2c, b2c, b2c};
        C2[t] = __builtin_amdgcn_mfma_f32_16x16x32_f16(A2L[t], BL2, c, 0, 0, 0);
    }

    #pragma unroll
    for (int t = 0; t < 8; ++t) {
        int tt = t & 3;
        #pragma unroll
        for (int i = 0; i < 4; ++i) {
            int rr = 4 * q + i;
            int nn = (t < 4) ? __shfl(s0, 16 * tt + rr, 64) : __shfl(s1, 16 * tt + rr, 64);
            int et = ebase + 16 * t + rr;
            if (et < E) {
                int bits = __float_as_int(fmaxf(C2[t][i], 0.0f));
                if (!fb) atomicMax(&lmax[(nn - n_first) * 16 + e16], bits);
                else     atomicMax(&aggi[(size_t)nn * 16 + e16], bits);
            }
        }
    }
    __syncthreads();
    if (!fb) {
        int tot = span * 16;
        for (int idx = tid; idx < tot; idx += 256) {
            int row = idx >> 4;
            int nn = n_first + row;
            int v = lmax[idx];
            if (nn == n_first || nn == n_last) {
                if (v != 0) atomicMax(&aggi[(size_t)nn * 16 + (idx & 15)], v);
            } else {
                aggi[(size_t)nn * 16 + (idx & 15)] = v;
            }
        }
    }
}

// ===========================================================================
// Dense per-node head: h2 -> relu(h2@l1+b) @ l2 + b
// ===========================================================================
__global__ __launch_bounds__(256) void head_out(
    const int* __restrict__ aggi,
    const float* __restrict__ l1w, const float* __restrict__ l1b,
    const float* __restrict__ l2w, const float* __restrict__ l2b,
    float* __restrict__ out, int N)
{
    int n = blockIdx.x * 256 + threadIdx.x;
    if (n >= N) return;
    const float4* ar = (const float4*)(aggi + (size_t)n * 16);
    float4 A0 = ar[0], A1 = ar[1], A2 = ar[2], A3 = ar[3];
    float acc[16] = {A0.x, A0.y, A0.z, A0.w, A1.x, A1.y, A1.z, A1.w,
                     A2.x, A2.y, A2.z, A2.w, A3.x, A3.y, A3.z, A3.w};
    float t2[16];
    #pragma unroll
    for (int j = 0; j < 16; ++j) t2[j] = l1b[j];
    #pragma unroll
    for (int k = 0; k < 16; ++k) {
        float ak = acc[k];
        #pragma unroll
        for (int j = 0; j < 16; ++j) t2[j] = fmaf(ak, l1w[k * 16 + j], t2[j]);
    }
    float r2 = l2b[0];
    #pragma unroll
    for (int j = 0; j < 16; ++j) r2 = fmaf(fmaxf(t2[j], 0.0f), l2w[j], r2);
    out[n] = r2;
}

// ===========================================================================
extern "C" void kernel_launch(void* const* d_in, const int* in_sizes, int n_in,
                              void* d_out, int out_size, void* d_ws, size_t ws_size,
                              hipStream_t stream)
{
    const float* x     = (const float*)d_in[0];
    const int*   ei    = (const int*)  d_in[1];
    const float* ea    = (const float*)d_in[2];
    const float* c1_w1 = (const float*)d_in[3];
    const float* c1_b1 = (const float*)d_in[4];
    const float* c1_w2 = (const float*)d_in[5];
    const float* c1_b2 = (const float*)d_in[6];
    const float* c2_w1 = (const float*)d_in[7];
    const float* c2_b1 = (const float*)d_in[8];
    const float* c2_w2 = (const float*)d_in[9];
    const float* c2_b2 = (const float*)d_in[10];
    const float* l1_w  = (const float*)d_in[11];
    const float* l1_b  = (const float*)d_in[12];
    const float* l2_w  = (const float*)d_in[13];
    const float* l2_b  = (const float*)d_in[14];
    float* out = (float*)d_out;

    const int N = in_sizes[0] / 4;   // 100000
    const int E = in_sizes[2] / 8;   // 1600000
    const int nbk = (N + (1 << NSH) - 1) >> NSH;   // 196 buckets
    const int epb = (E + NBLK - 1) / NBLK;         // edges per hist/part block
    const int ntot = nbk * NBLK;                   // 200704 count entries
    const int nch = (ntot + CHUNK - 1) / CHUNK;    // 197

    const int BLK = 256;
    const int mgrid = (E + 511) / 512;     // 512 CSR edges per block
    const int ngrid = (N + 255) / 256;
    const int cgrid = (N * 8 + 255) / 256; // cvt_h1: N*16/2 words

    size_t szXh  = ((size_t)N * 8 + 255) & ~(size_t)255;    // 0.8 MB
    size_t szH1  = ((size_t)N * 32 + 255) & ~(size_t)255;   // 3.2 MB
    size_t szSd  = ((size_t)E * 8 + 255) & ~(size_t)255;    // 12.8 MB
    size_t szAt  = ((size_t)E * 16 + 255) & ~(size_t)255;   // 25.6 MB
    size_t szCnt = ((size_t)ntot * 4 + 255) & ~(size_t)255; // 0.8 MB
    size_t szAgg = ((size_t)N * 64 + 255) & ~(size_t)255;   // 6.4 MB

    size_t xh_off   = 0;
    size_t h1_off   = xh_off   + szXh;
    size_t rsd_off  = h1_off   + szH1;
    size_t rat_off  = rsd_off  + szSd;
    size_t p1sd_off = rat_off  + szAt;
    size_t p1at_off = p1sd_off + szSd;
    size_t cnt_off  = p1at_off + szAt;
    size_t off_off  = cnt_off  + szCnt;
    size_t cs_off   = off_off  + szCnt;
    size_t cf_off   = cs_off   + 4096;
    // agg arrays overlay P1 (dead after bucket_csr)
    size_t agg1_off = p1sd_off;
    size_t agg2_off = p1sd_off + szAgg;

    _Float16* xh   = (_Float16*)((char*)d_ws + xh_off);
    _Float16* h1   = (_Float16*)((char*)d_ws + h1_off);
    int2*     rsd  = (int2*)    ((char*)d_ws + rsd_off);
    uint4*    rat  = (uint4*)   ((char*)d_ws + rat_off);
    int2*     p1sd = (int2*)    ((char*)d_ws + p1sd_off);
    uint4*    p1at = (uint4*)   ((char*)d_ws + p1at_off);
    int*      cnt  = (int*)     ((char*)d_ws + cnt_off);
    int*      off  = (int*)     ((char*)d_ws + off_off);
    int*      csum = (int*)     ((char*)d_ws + cs_off);
    int*      coff = (int*)     ((char*)d_ws + cf_off);
    int*      agg1 = (int*)     ((char*)d_ws + agg1_off);
    int*      agg2 = (int*)     ((char*)d_ws + agg2_off);

    hist_x<<<NBLK, 512, 0, stream>>>(ei, x, cnt, xh, E, N, nbk, epb);
    scan_chunk_sums<<<nch, BLK, 0, stream>>>(cnt, csum, ntot);
    scan_chunk_off<<<1, 256, 0, stream>>>(csum, coff, nch);
    scan_within_excl<<<nch, BLK, 0, stream>>>(cnt, off, coff, ntot);
    partition<<<NBLK, 512, 0, stream>>>(ei, ea, off, p1sd, p1at, E, nbk, epb);
    bucket_csr<<<nbk, 1024, 0, stream>>>(p1sd, p1at, off, rsd, rat, E, nbk);
    // P1 dead; agg arrays overlay it
    hipMemsetAsync(agg1, 0, (size_t)N * 64, stream);
    hipMemsetAsync(agg2, 0, (size_t)N * 64, stream);
    edge_mlp1_agg<<<mgrid, BLK, 0, stream>>>(xh, rsd, rat,
                                             c1_w1, c1_b1, c1_w2, c1_b2,
                                             agg1, E);
    cvt_h1<<<cgrid, BLK, 0, stream>>>(agg1, (unsigned int*)h1, N * 8);
    edge_mlp2_agg<<<mgrid, BLK, 0, stream>>>(h1, rsd, rat,
                                             c2_w1, c2_b1, c2_w2, c2_b2,
                                             agg2, E);
    head_out<<<ngrid, BLK, 0, stream>>>(agg2, l1_w, l1_b, l2_w, l2_b, out, N);
}